// Round 10
// baseline (408.084 us; speedup 1.0000x reference)
//
#include <hip/hip_runtime.h>
#include <hip/hip_bf16.h>

#define B_GRAPH 128
#define ETOT    (128*4096)
#define N0G     (128*512)
#define HF      128
// banked stats: [8][256] floats (bank = XCD-ish id) to keep atomics uncontended
#define STSZ    2048

// ---------------- merged: per-graph init (blocks 0..127) + level-0 GEMM (blocks 128..639) ----------------
// GEMM branch: BOTH operands staged in LDS (A swizzled 32KB + W linear 32KB = 64KB).
// Inner loop touches no global memory -> VALU-bound by construction.
union IGSmem {
    struct { float As[128*64]; float Ws[64*HF]; } g;     // 64 KB exactly (precedent: k_prop_lds<512>)
    struct { int cnt8[8][512]; int cur[512]; float dvl[512]; int wsum[4]; } ini;   // ~20 KB
};

__global__ __launch_bounds__(256) void k_init_gemm(
    const float* __restrict__ A, const float* __restrict__ Wg, float* __restrict__ C,
    const int* __restrict__ s_in, const int* __restrict__ d_in_,
    int2* __restrict__ csr, int2* __restrict__ rb2, float* __restrict__ dinvv,
    float* __restrict__ gacc, float* __restrict__ statsH,
    float* __restrict__ st0, float* __restrict__ st1, float* __restrict__ st2)
{
    __shared__ IGSmem sm;
    int t = threadIdx.x;
    if (blockIdx.x >= 128){
        // ---- GEMM: 128 rows x 128 cols per block, 8x8 per thread, A+W in LDS ----
        int tx = t & 15, ty = t >> 4;
        int r0 = (blockIdx.x - 128)*128, c0 = tx*4;
        int sw = ty & 3;                                  // read-side swizzle key (A)
        float acc[8][8];
        #pragma unroll
        for (int j=0;j<8;++j)
            #pragma unroll
            for (int l=0;l<8;++l) acc[j][l] = 0.f;
        for (int kh = 0; kh < 2; ++kh){
            __syncthreads();
            #pragma unroll
            for (int p = 0; p < 8; ++p){                  // stage 128x64 A chunk, coalesced, swizzled
                int idx = p*256 + t;
                int row = idx >> 4, col4 = idx & 15;
                float4 v = *(const float4*)(A + (size_t)(r0+row)*HF + kh*64 + col4*4);
                *(float4*)&sm.g.As[row*64 + ((col4 ^ ((row>>3)&3))<<2)] = v;
            }
            {
                float4* d4 = (float4*)sm.g.Ws;            // stage 64x128 W half, linear
                const float4* s4 = (const float4*)(Wg + kh*64*HF);
                #pragma unroll
                for (int i2 = 0; i2 < 8; ++i2) d4[t + i2*256] = s4[t + i2*256];
            }
            __syncthreads();
            for (int k4 = 0; k4 < 16; ++k4){
                float4 av[8];
                #pragma unroll
                for (int j=0;j<8;++j)
                    av[j] = *(const float4*)&sm.g.As[(ty*8+j)*64 + ((k4 ^ sw)<<2)];
                #pragma unroll
                for (int kk=0; kk<4; ++kk){
                    int kl = k4*4 + kk;
                    float4 w0 = *(const float4*)(sm.g.Ws + kl*HF + c0);
                    float4 w1 = *(const float4*)(sm.g.Ws + kl*HF + c0 + 64);
                    #pragma unroll
                    for (int j=0;j<8;++j){
                        float a = reinterpret_cast<const float*>(&av[j])[kk];
                        acc[j][0] += a*w0.x; acc[j][1] += a*w0.y; acc[j][2] += a*w0.z; acc[j][3] += a*w0.w;
                        acc[j][4] += a*w1.x; acc[j][5] += a*w1.y; acc[j][6] += a*w1.z; acc[j][7] += a*w1.w;
                    }
                }
            }
        }
        #pragma unroll
        for (int j=0;j<8;++j){
            *(float4*)(C + (size_t)(r0+ty*8+j)*HF + c0)      = make_float4(acc[j][0],acc[j][1],acc[j][2],acc[j][3]);
            *(float4*)(C + (size_t)(r0+ty*8+j)*HF + c0 + 64) = make_float4(acc[j][4],acc[j][5],acc[j][6],acc[j][7]);
        }
    } else {
        int g = blockIdx.x;
        int wid = t >> 5;                      // 32-lane group id: 8 privatized histogram copies
        for (int l = t; l < 4096; l += 256) ((int*)sm.ini.cnt8)[l] = 0;
        gacc[g*256 + t] = 0.f;
        if (g == 0){
            if (t < 256){ statsH[t] = 0.f; if (t < 128) statsH[256+t] = 0.f; }
            for (int i = t; i < STSZ; i += 256){ st0[i] = 0.f; st1[i] = 0.f; st2[i] = 0.f; }
        }
        __syncthreads();
        for (int j = t; j < 4096; j += 256){
            int e = g*4096 + j;
            atomicAdd(&sm.ini.cnt8[wid][d_in_[e] & 511], 1);
        }
        __syncthreads();
        int c0 = 0, c1 = 0;
        #pragma unroll
        for (int w = 0; w < 8; ++w){ c0 += sm.ini.cnt8[w][2*t]; c1 += sm.ini.cnt8[w][2*t+1]; }
        int pairsum = c0 + c1;
        // wave-shuffle inclusive scan over 256 threads (4 waves), 1 barrier
        int lane = t & 63, wv = t >> 6;
        int v = pairsum;
        #pragma unroll
        for (int off = 1; off < 64; off <<= 1){
            int nv = __shfl_up(v, off);
            if (lane >= off) v += nv;
        }
        if (lane == 63) sm.ini.wsum[wv] = v;
        __syncthreads();
        for (int ww = 0; ww < wv; ++ww) v += sm.ini.wsum[ww];
        int begpair = v - pairsum;
        sm.ini.cur[2*t]   = begpair;
        sm.ini.cur[2*t+1] = begpair + c0;
        // stash per-node count in cnt8[0] for the rb2 pass
        sm.ini.cnt8[0][2*t]   = c0;
        sm.ini.cnt8[0][2*t+1] = c1;
        __syncthreads();
        for (int l = t; l < 512; l += 256){
            int cl = sm.ini.cnt8[0][l];
            rb2[g*512 + l] = make_int2(g*4096 + sm.ini.cur[l], cl);
            float dv = rsqrtf((float)cl + 1.f);
            sm.ini.dvl[l] = dv;
            dinvv[g*512 + l] = dv;
        }
        __syncthreads();
        for (int j = t; j < 4096; j += 256){
            int e = g*4096 + j;
            int sg = s_in[e], dl = d_in_[e] & 511;
            int p = atomicAdd(&sm.ini.cur[dl], 1);
            csr[g*4096 + (p & 4095)] = make_int2(sg, __float_as_int(sm.ini.dvl[sg & 511]));
        }
    }
}

// ---------------- LDS-staged prop + BN stats (feature-quarter blocks; NN = nodes/graph) ----------------
template<int NN>
__global__ __launch_bounds__(512) void k_prop_lds(
    const float* __restrict__ Y, const float* __restrict__ cb,
    const int2* __restrict__ rb2, const int2* __restrict__ cp,
    const float* __restrict__ dinv, float* __restrict__ X, float* __restrict__ st)
{
    constexpr int TP = 512 / NN;          // threads per node (1 or 2)
    constexpr int FQ = 8 / TP;            // float4s per thread
    __shared__ float4 ly[NN * 8];         // 64 KB at NN=512, 32 KB at NN=256
    int b = blockIdx.x;
    int g = b >> 2, q = b & 3;
    int t = threadIdx.x;
    const float4* Y4 = (const float4*)Y + (size_t)g*NN*32 + q*8;
    for (int i = t; i < NN*8; i += 512){
        int row = i >> 3, slot = i & 7;
        ly[row*8 + ((slot + row) & 7)] = Y4[(size_t)row*32 + slot];
    }
    __syncthreads();
    int r   = t & (NN - 1);
    int sub = t / NN;
    int S0  = sub * FQ;
    int vg  = g*NN + r;
    float dv = dinv[vg];
    int2 rb = rb2[vg];
    int e0  = (rb.x - g*4096) & 4095;
    int len = min(max(rb.y, 0), 4096 - e0);
    const int2* cpg = cp + g*4096 + e0;
    float4 acc[FQ];
    #pragma unroll
    for (int s = 0; s < FQ; ++s) acc[s] = make_float4(0.f,0.f,0.f,0.f);
    for (int j = 0; j < len; ++j){
        int2 e = cpg[j];
        int c = e.x & (NN - 1);
        float en = __int_as_float(e.y);
        #pragma unroll
        for (int s = 0; s < FQ; ++s){
            float4 h = ly[c*8 + ((S0 + s + c) & 7)];
            acc[s].x += en*h.x; acc[s].y += en*h.y; acc[s].z += en*h.z; acc[s].w += en*h.w;
        }
    }
    const float4* cb4 = (const float4*)cb + q*8;
    float4* X4 = (float4*)X + q*8;
    #pragma unroll
    for (int s = 0; s < FQ; ++s){
        float4 y = ly[r*8 + ((S0 + s + r) & 7)];
        float4 cbv = cb4[S0 + s];
        acc[s].x = y.x*dv*dv + dv*acc[s].x + cbv.x;
        acc[s].y = y.y*dv*dv + dv*acc[s].y + cbv.y;
        acc[s].z = y.z*dv*dv + dv*acc[s].z + cbv.z;
        acc[s].w = y.w*dv*dv + dv*acc[s].w + cbv.w;
        X4[(size_t)vg*32 + S0 + s] = acc[s];
    }
    __syncthreads();
    float* lf = (float*)ly;
    #pragma unroll
    for (int s = 0; s < FQ; ++s) *(float4*)&lf[r*32 + (S0 + s)*4] = acc[s];
    __syncthreads();
    float ssum = 0.f, qsum = 0.f;
    {
        int col = t & 31, grp = t >> 5;
        for (int rr = grp; rr < NN; rr += 16){
            float v = lf[rr*32 + col];
            ssum += v; qsum += v*v;
        }
    }
    __syncthreads();
    lf[t] = ssum; lf[512 + t] = qsum;
    __syncthreads();
    if (t < 64){
        int col = t & 31, half = t >> 5;
        float a = 0.f;
        #pragma unroll
        for (int i = 0; i < 16; ++i) a += lf[half*512 + i*32 + col];
        atomicAdd(&st[(b & 7)*256 + half*128 + q*32 + col], a);
    }
}

// ---------------- chip-wide prop + banked BN stats (small levels, XCD swizzle) ----------------
__global__ __launch_bounds__(256) void k_prop_stats(const float* __restrict__ Y, const float* __restrict__ cb,
                                                    const int2* __restrict__ rb2, const int2* __restrict__ cp,
                                                    const float* __restrict__ dinv,
                                                    float* __restrict__ X, float* __restrict__ st,
                                                    int n, int lb, int Nn){
    __shared__ float rs[1024], rq[1024];
    int xcd = blockIdx.x & 7, c = blockIdx.x >> 3;
    int g = xcd*16 + (c >> lb);
    int m = c & ((1 << lb) - 1);
    int nd = threadIdx.x >> 5;
    int v = g*n + m*8 + nd;
    int f4 = threadIdx.x & 31;
    float dv = dinv[v];
    float4 y = *(const float4*)(Y + (size_t)v*HF + f4*4);
    float4 acc = make_float4(0.f, 0.f, 0.f, 0.f);
    int2 rb = rb2[v];
    int len = min(max(rb.y, 0), 4096);
    int e0 = rb.x, e1 = rb.x + len;
    for (int j = e0; j < e1; ++j){
        int2 e = cp[j];
        int s = e.x & (Nn - 1);
        float en = __int_as_float(e.y);
        float4 h = *(const float4*)(Y + (size_t)s*HF + f4*4);
        acc.x += en*h.x; acc.y += en*h.y; acc.z += en*h.z; acc.w += en*h.w;
    }
    int f = f4*4;
    acc.x = y.x*dv*dv + dv*acc.x + cb[f];
    acc.y = y.y*dv*dv + dv*acc.y + cb[f+1];
    acc.z = y.z*dv*dv + dv*acc.z + cb[f+2];
    acc.w = y.w*dv*dv + dv*acc.w + cb[f+3];
    *(float4*)(X + (size_t)v*HF + f) = acc;
    *(float4*)&rs[nd*HF + f] = acc;
    *(float4*)&rq[nd*HF + f] = make_float4(acc.x*acc.x, acc.y*acc.y, acc.z*acc.z, acc.w*acc.w);
    __syncthreads();
    if (threadIdx.x < 128){
        int tt = threadIdx.x;
        float s = 0.f, q = 0.f;
        #pragma unroll
        for (int j = 0; j < 8; ++j){ s += rs[j*HF + tt]; q += rq[j*HF + tt]; }
        atomicAdd(&st[xcd*256 + tt], s);
        atomicAdd(&st[xcd*256 + 128 + tt], q);
    }
}

// ---------------- chip-wide attention score s0 = relu(bn(h))·aw ----------------
__global__ __launch_bounds__(256) void k_score(
    const float* __restrict__ H, const float* __restrict__ stats,
    const float* __restrict__ gw, const float* __restrict__ gb,
    const float* __restrict__ aw, float* __restrict__ s0G, float invN)
{
    __shared__ float bna[128], bnb[128], awl[128];
    int t = threadIdx.x;
    if (t < 128){
        float s = 0.f, q = 0.f;
        #pragma unroll
        for (int b2 = 0; b2 < 8; ++b2){ s += stats[b2*256 + t]; q += stats[b2*256 + 128 + t]; }
        float mean = s*invN;
        float var  = q*invN - mean*mean;
        float iv   = rsqrtf(var + 1e-5f);
        bna[t] = iv*gw[t];
        bnb[t] = gb[t] - mean*iv*gw[t];
        awl[t] = aw[t];
    }
    __syncthreads();
    int v = blockIdx.x*128 + (t >> 1);
    int h = t & 1;
    const float* hp = H + (size_t)v*HF + h*64;
    float part = 0.f;
    #pragma unroll
    for (int j = 0; j < 16; ++j){
        float4 x = *(const float4*)(hp + j*4);
        int f = h*64 + j*4;
        float4 a4 = *(const float4*)&bna[f];
        float4 b4 = *(const float4*)&bnb[f];
        float4 w4 = *(const float4*)&awl[f];
        part += fmaxf(x.x*a4.x + b4.x, 0.f)*w4.x
              + fmaxf(x.y*a4.y + b4.y, 0.f)*w4.y
              + fmaxf(x.z*a4.z + b4.z, 0.f)*w4.z
              + fmaxf(x.w*a4.w + b4.w, 0.f)*w4.w;
    }
    float oth = __shfl_xor(part, 1);
    if (h == 0) s0G[v] = part + oth;
}

// ---------------- staged gather-GEMM: A rows gathered+BN+ReLU+tanh during stage, W from L2 ----------------
template<int RPT>   // rows per thread (8 -> 128-row tile, 4 -> 64-row tile)
__global__ __launch_bounds__(256) void k_gemm_gs(
    const float* __restrict__ Hsrc, const float* __restrict__ stats,
    const float* __restrict__ gw, const float* __restrict__ gb,
    const int* __restrict__ siG, const float* __restrict__ tssG,
    const float* __restrict__ Wg, float* __restrict__ C,
    float invN, int lk, int ln)
{
    constexpr int RPB = RPT*16;
    constexpr int SH  = (RPT == 8) ? 3 : 2;
    __shared__ float As[RPB*64];
    __shared__ float bna[128], bnb[128];
    int t = threadIdx.x;
    if (t < 128){
        float s = 0.f, q = 0.f;
        #pragma unroll
        for (int b2 = 0; b2 < 8; ++b2){ s += stats[b2*256 + t]; q += stats[b2*256 + 128 + t]; }
        float mean = s*invN;
        float var  = q*invN - mean*mean;
        float iv   = rsqrtf(var + 1e-5f);
        bna[t] = iv*gw[t];
        bnb[t] = gb[t] - mean*iv*gw[t];
    }
    int tx = t & 15, ty = t >> 4;
    int r0 = blockIdx.x*RPB, c0 = tx*4;
    int nmask = (1 << ln) - 1;
    int sw = ty & 3;
    float acc[RPT][8];
    #pragma unroll
    for (int j=0;j<RPT;++j)
        #pragma unroll
        for (int l=0;l<8;++l) acc[j][l] = 0.f;
    for (int kh = 0; kh < 2; ++kh){
        __syncthreads();
        #pragma unroll
        for (int p = 0; p < RPB/16; ++p){
            int idx = p*256 + t;
            int row = idx >> 4, col4 = idx & 15;
            int rg = r0 + row;
            int g = rg >> lk;
            int old = siG[rg] & nmask;
            float ts = tssG[rg];
            int f = kh*64 + col4*4;
            float4 v = *(const float4*)(Hsrc + (size_t)((g<<ln)+old)*HF + f);
            float4 ba = *(const float4*)&bna[f];
            float4 bb = *(const float4*)&bnb[f];
            v.x = fmaxf(v.x*ba.x + bb.x, 0.f)*ts;
            v.y = fmaxf(v.y*ba.y + bb.y, 0.f)*ts;
            v.z = fmaxf(v.z*ba.z + bb.z, 0.f)*ts;
            v.w = fmaxf(v.w*ba.w + bb.w, 0.f)*ts;
            *(float4*)&As[row*64 + ((col4 ^ ((row>>SH)&3))<<2)] = v;
        }
        __syncthreads();
        const float* Wk = Wg + kh*64*HF;
        for (int k4 = 0; k4 < 16; ++k4){
            float4 av[RPT];
            #pragma unroll
            for (int j=0;j<RPT;++j)
                av[j] = *(const float4*)&As[(ty*RPT+j)*64 + ((k4 ^ sw)<<2)];
            #pragma unroll
            for (int kk=0; kk<4; ++kk){
                int kl = k4*4 + kk;
                float4 w0 = *(const float4*)(Wk + kl*HF + c0);
                float4 w1 = *(const float4*)(Wk + kl*HF + c0 + 64);
                #pragma unroll
                for (int j=0;j<RPT;++j){
                    float a = reinterpret_cast<const float*>(&av[j])[kk];
                    acc[j][0] += a*w0.x; acc[j][1] += a*w0.y; acc[j][2] += a*w0.z; acc[j][3] += a*w0.w;
                    acc[j][4] += a*w1.x; acc[j][5] += a*w1.y; acc[j][6] += a*w1.z; acc[j][7] += a*w1.w;
                }
            }
        }
    }
    #pragma unroll
    for (int j=0;j<RPT;++j){
        *(float4*)(C + (size_t)(r0+ty*RPT+j)*HF + c0)      = make_float4(acc[j][0],acc[j][1],acc[j][2],acc[j][3]);
        *(float4*)(C + (size_t)(r0+ty*RPT+j)*HF + c0 + 64) = make_float4(acc[j][4],acc[j][5],acc[j][6],acc[j][7]);
    }
}

// ---------------- small-level gather-GEMM: 32-row tiles, unstaged (max grid parallelism) ----------------
__global__ __launch_bounds__(256) void k_gemm_g32(
    const float* __restrict__ Hsrc, const float* __restrict__ stats,
    const float* __restrict__ gw, const float* __restrict__ gb,
    const int* __restrict__ siG, const float* __restrict__ tssG,
    const float* __restrict__ Wg, float* __restrict__ C,
    float invN, int lk, int ln)
{
    __shared__ float bna[128], bnb[128];
    int t = threadIdx.x;
    if (t < 128){
        float s = 0.f, q = 0.f;
        #pragma unroll
        for (int b2 = 0; b2 < 8; ++b2){ s += stats[b2*256 + t]; q += stats[b2*256 + 128 + t]; }
        float mean = s*invN;
        float var  = q*invN - mean*mean;
        float iv   = rsqrtf(var + 1e-5f);
        bna[t] = iv*gw[t];
        bnb[t] = gb[t] - mean*iv*gw[t];
    }
    __syncthreads();
    int tx = t & 15, ty = t >> 4;
    int r0 = blockIdx.x*32 + ty*2, c0 = tx*4;
    int nmask = (1 << ln) - 1;
    int rbase[2]; float ts_[2];
    #pragma unroll
    for (int j = 0; j < 2; ++j){
        int rg = r0 + j;
        int g = rg >> lk;
        int old = siG[rg] & nmask;
        rbase[j] = ((g << ln) + old) * HF;
        ts_[j] = tssG[rg];
    }
    float acc[2][8];
    #pragma unroll
    for (int j=0;j<2;++j)
        #pragma unroll
        for (int l=0;l<8;++l) acc[j][l] = 0.f;
    for (int k4 = 0; k4 < 32; ++k4){
        int f = k4*4;
        float4 ba = *(const float4*)&bna[f];
        float4 bb = *(const float4*)&bnb[f];
        float4 av[2];
        #pragma unroll
        for (int j=0;j<2;++j){
            av[j] = *(const float4*)(Hsrc + (size_t)rbase[j] + f);
            av[j].x = fmaxf(av[j].x*ba.x + bb.x, 0.f)*ts_[j];
            av[j].y = fmaxf(av[j].y*ba.y + bb.y, 0.f)*ts_[j];
            av[j].z = fmaxf(av[j].z*ba.z + bb.z, 0.f)*ts_[j];
            av[j].w = fmaxf(av[j].w*ba.w + bb.w, 0.f)*ts_[j];
        }
        #pragma unroll
        for (int kk=0; kk<4; ++kk){
            int kl = f + kk;
            float4 w0 = *(const float4*)(Wg + kl*HF + c0);
            float4 w1 = *(const float4*)(Wg + kl*HF + c0 + 64);
            #pragma unroll
            for (int j=0;j<2;++j){
                float a = reinterpret_cast<const float*>(&av[j])[kk];
                acc[j][0] += a*w0.x; acc[j][1] += a*w0.y; acc[j][2] += a*w0.z; acc[j][3] += a*w0.w;
                acc[j][4] += a*w1.x; acc[j][5] += a*w1.y; acc[j][6] += a*w1.z; acc[j][7] += a*w1.w;
            }
        }
    }
    #pragma unroll
    for (int j=0;j<2;++j){
        *(float4*)(C + (size_t)(r0+j)*HF + c0)      = make_float4(acc[j][0],acc[j][1],acc[j][2],acc[j][3]);
        *(float4*)(C + (size_t)(r0+j)*HF + c0 + 64) = make_float4(acc[j][4],acc[j][5],acc[j][6],acc[j][7]);
    }
}

// ---------------- per-graph kernel: pvec/top-k/CSR-rebuild/readout (+head1 at last) ----------------
struct __align__(16) PSmem {
    int2  eds[4096];
    int2  rbl[512];
    float dvv[512], p0[512], p1[512], p2[512];
    float ss[512]; int si[512]; float tss[256]; int nid[512];
    int   cnt_[256]; int wsum[4]; float dvn[256];
    float bna[128], bnb[128]; float red[1024];
};

__global__ __launch_bounds__(1024) void k_pool(
    const float* __restrict__ H, const float* __restrict__ stats,
    const float* __restrict__ gw, const float* __restrict__ gb,
    const float* __restrict__ th,
    const int2* __restrict__ rb2, int2* __restrict__ csr, const float* __restrict__ dinv,
    const float* __restrict__ s0G,
    float* __restrict__ gacc, int2* __restrict__ rb2n, float* __restrict__ dinvn,
    float* __restrict__ stZero, int* __restrict__ siG, float* __restrict__ tssG,
    const float* __restrict__ lin1W, const float* __restrict__ lin1b,
    float* __restrict__ t1g, float* __restrict__ statsH,
    float invN, float ca2, float cc2, float ca3, float cc3,
    int n, int last)
{
    int g = blockIdx.x, t = threadIdx.x;
    int k = n >> 1;
    __shared__ PSmem sm;

    if (t < 256) stZero[(g & 7)*256 + t] = 0.f;
    if (t < 128){
        float s = 0.f, q = 0.f;
        #pragma unroll
        for (int b2 = 0; b2 < 8; ++b2){ s += stats[b2*256 + t]; q += stats[b2*256 + 128 + t]; }
        float mean = s*invN;
        float var  = q*invN - mean*mean;
        float iv   = rsqrtf(var + 1e-5f);
        sm.bna[t] = iv*gw[t];
        sm.bnb[t] = gb[t] - mean*iv*gw[t];
    }
    for (int l = t; l < n; l += 1024){
        int2 rb = rb2[g*n + l];
        int bx = (rb.x - g*4096) & 4095;
        int by = min(max(rb.y, 0), 4096 - bx);
        sm.rbl[l] = make_int2(bx, by);
        sm.dvv[l] = dinv[g*n + l];
        sm.p0[l]  = s0G[g*n + l];
    }
    __syncthreads();
    int medg = sm.rbl[n-1].x + sm.rbl[n-1].y;
    for (int j = t; j < medg; j += 1024){
        int2 e = csr[g*4096 + j];
        sm.eds[j] = make_int2(e.x & (n-1), e.y);
    }
    __syncthreads();
    for (int l = t; l < n; l += 1024){
        int2 rc = sm.rbl[l];
        float acc = 0.f;
        for (int j = 0; j < rc.y; ++j){
            int2 e = sm.eds[rc.x + j];
            acc += __int_as_float(e.y) * sm.p0[e.x];
        }
        float dv = sm.dvv[l];
        sm.p1[l] = 2.f*(sm.p0[l]*dv*dv + dv*acc);
    }
    __syncthreads();
    for (int l = t; l < n; l += 1024){
        int2 rc = sm.rbl[l];
        float acc = 0.f;
        for (int j = 0; j < rc.y; ++j){
            int2 e = sm.eds[rc.x + j];
            acc += __int_as_float(e.y) * sm.p1[e.x];
        }
        float dv = sm.dvv[l];
        sm.p2[l] = ca2*(sm.p1[l]*dv*dv + dv*acc) + cc2*sm.p0[l];
    }
    __syncthreads();
    float t0v = th[0], t1v = th[1], t2c = th[2], t3v = th[3];
    for (int l = t; l < n; l += 1024){
        int2 rc = sm.rbl[l];
        float acc = 0.f;
        for (int j = 0; j < rc.y; ++j){
            int2 e = sm.eds[rc.x + j];
            acc += __int_as_float(e.y) * sm.p2[e.x];
        }
        float dv = sm.dvv[l];
        float tv = sm.p2[l]*dv*dv + dv*acc;
        float p3 = ca3*tv + cc3*sm.p1[l];
        sm.ss[l] = t0v*sm.p0[l] + t1v*sm.p1[l] + t2c*sm.p2[l] + t3v*p3;
    }
    __syncthreads();
    for (int l = t; l < n; l += 1024){
        float sl = sm.ss[l];
        int r = 0;
        for (int j = 0; j < n; j += 4){
            float4 s4 = *(const float4*)&sm.ss[j];
            r += (s4.x > sl) || (s4.x == sl && (j    ) < l);
            r += (s4.y > sl) || (s4.y == sl && (j + 1) < l);
            r += (s4.z > sl) || (s4.z == sl && (j + 2) < l);
            r += (s4.w > sl) || (s4.w == sl && (j + 3) < l);
        }
        if (r < k){
            sm.nid[l] = r;
            sm.si[r]  = l;
            float tv = tanhf(sl);
            sm.tss[r] = tv;
            siG[g*k + r]  = l;
            tssG[g*k + r] = tv;
        } else {
            sm.nid[l] = -1;
        }
    }
    __syncthreads();
    if (!last){
        if (t < k){
            int l = sm.si[t] & (n-1);
            int2 rc = sm.rbl[l];
            int c2 = 0;
            for (int j = 0; j < rc.y; ++j) c2 += (sm.nid[sm.eds[rc.x + j].x] >= 0);
            sm.cnt_[t] = c2;
        }
        __syncthreads();
        int c = (t < 256) ? ((t < k) ? sm.cnt_[t] : 0) : 0;
        int vscan = c;
        if (t < 256){
            int lane = t & 63;
            #pragma unroll
            for (int off = 1; off < 64; off <<= 1){
                int nv = __shfl_up(vscan, off);
                if (lane >= off) vscan += nv;
            }
            if (lane == 63) sm.wsum[t >> 6] = vscan;
        }
        __syncthreads();
        int beg = 0;
        if (t < k){
            int wv = t >> 6;
            int add = 0;
            for (int ww = 0; ww < wv; ++ww) add += sm.wsum[ww];
            vscan += add;
            beg = vscan - c;
            rb2n[g*k + t] = make_int2(g*4096 + beg, c);
            float dv = rsqrtf((float)c + 1.f);
            dinvn[g*k + t] = dv;
            sm.dvn[t] = dv;
        }
        __syncthreads();
        if (t < k){
            int l = sm.si[t] & (n-1);
            int2 rc = sm.rbl[l];
            int p = beg;
            for (int j = 0; j < rc.y; ++j){
                int ns = sm.nid[sm.eds[rc.x + j].x];
                if (ns >= 0){ csr[g*4096 + (p & 4095)] = make_int2(g*k + ns, __float_as_int(sm.dvn[ns])); ++p; }
            }
        }
        __syncthreads();
    }
    {
        int f4 = t & 31, rl = t >> 5;
        int f = f4*4;
        float4 a4 = *(const float4*)&sm.bna[f];
        float4 b4 = *(const float4*)&sm.bnb[f];
        float4 mx = make_float4(-3.4e38f,-3.4e38f,-3.4e38f,-3.4e38f);
        float4 smv = make_float4(0.f,0.f,0.f,0.f);
        for (int r = rl; r < k; r += 32){
            int old = sm.si[r] & (n-1);
            float4 hv = *(const float4*)(H + ((size_t)g*n + old)*HF + f);
            float ts = sm.tss[r];
            float4 v;
            v.x = fmaxf(hv.x*a4.x + b4.x, 0.f)*ts;
            v.y = fmaxf(hv.y*a4.y + b4.y, 0.f)*ts;
            v.z = fmaxf(hv.z*a4.z + b4.z, 0.f)*ts;
            v.w = fmaxf(hv.w*a4.w + b4.w, 0.f)*ts;
            mx.x = fmaxf(mx.x, v.x); mx.y = fmaxf(mx.y, v.y);
            mx.z = fmaxf(mx.z, v.z); mx.w = fmaxf(mx.w, v.w);
            smv.x += v.x; smv.y += v.y; smv.z += v.z; smv.w += v.w;
        }
        float* scr = (float*)sm.eds;
        *(float4*)&scr[rl*128 + f]        = mx;
        *(float4*)&scr[4096 + rl*128 + f] = smv;
        __syncthreads();
        if (t < 128){
            float m = -3.4e38f, s = 0.f;
            #pragma unroll
            for (int j = 0; j < 32; ++j){
                m = fmaxf(m, scr[j*128 + t]);
                s += scr[4096 + j*128 + t];
            }
            gacc[g*256 + t] += m;
            gacc[g*256 + 128 + t] += s / (float)k;
        }
    }
    if (last){
        __syncthreads();
        int c = t & 127, h = t >> 7;
        float s = 0.f;
        int k0 = h*32;
        #pragma unroll
        for (int kk = 0; kk < 32; ++kk)
            s += gacc[g*256 + k0 + kk] * lin1W[(k0 + kk)*128 + c];
        sm.red[t] = s;
        __syncthreads();
        if (t < 512) sm.red[t] += sm.red[t+512];
        __syncthreads();
        if (t < 256) sm.red[t] += sm.red[t+256];
        __syncthreads();
        if (t < 128){
            float v = (sm.red[t] + sm.red[t+128]) * 0.2f + lin1b[t];
            t1g[g*128 + t] = v;
            atomicAdd(&statsH[t], v);
            atomicAdd(&statsH[128+t], v*v);
        }
    }
}

// ---------------- head tail kernels ----------------
__global__ __launch_bounds__(128) void k_head2(const float* __restrict__ t1, const float* __restrict__ gw,
                                               const float* __restrict__ gb, const float* __restrict__ W2,
                                               const float* __restrict__ b2, float* __restrict__ sh,
                                               float* __restrict__ t2){
    int r = blockIdx.x, t = threadIdx.x;
    int cc = t & 63, h = t >> 6;
    __shared__ float row[128];
    __shared__ float red[128];
    {
        float mean = sh[t] * (1.f/128.f);
        float var  = sh[128+t]*(1.f/128.f) - mean*mean;
        float iv   = rsqrtf(var + 1e-5f);
        float v = (t1[r*128+t] - mean)*iv*gw[t] + gb[t];
        row[t] = fmaxf(v, 0.f);
    }
    __syncthreads();
    float s = 0.f;
    #pragma unroll
    for (int kk = 0; kk < 64; ++kk)
        s += row[h*64+kk] * W2[(h*64+kk)*64 + cc];
    red[t] = s;
    __syncthreads();
    if (h == 0){
        float v = red[cc] + red[cc+64] + b2[cc];
        t2[r*64+cc] = v;
        atomicAdd(&sh[256+cc], v);
        atomicAdd(&sh[320+cc], v*v);
    }
}
__global__ __launch_bounds__(64) void k_head3(const float* __restrict__ t2, const float* __restrict__ gw,
                                              const float* __restrict__ gb, const float* __restrict__ W3,
                                              const float* __restrict__ b3, const float* __restrict__ sh,
                                              float* __restrict__ out){
    int r = blockIdx.x, t = threadIdx.x;
    float mean = sh[256+t]*(1.f/128.f);
    float var  = sh[320+t]*(1.f/128.f) - mean*mean;
    float iv   = rsqrtf(var + 1e-5f);
    float v = fmaxf((t2[r*64+t]-mean)*iv*gw[t] + gb[t], 0.f);
    float lg[10];
    #pragma unroll
    for (int j = 0; j < 10; ++j){
        float p = v * W3[t*10 + j];
        for (int off = 32; off; off >>= 1) p += __shfl_down(p, off);
        lg[j] = p;
    }
    if (t == 0){
        float m = -3.4e38f;
        #pragma unroll
        for (int j = 0; j < 10; ++j){ lg[j] += b3[j]; m = fmaxf(m, lg[j]); }
        float se = 0.f;
        #pragma unroll
        for (int j = 0; j < 10; ++j) se += expf(lg[j] - m);
        float l = logf(se) + m;
        #pragma unroll
        for (int j = 0; j < 10; ++j) out[r*10 + j] = lg[j] - l;
    }
}

extern "C" void kernel_launch(void* const* d_in, const int* in_sizes, int n_in,
                              void* d_out, int out_size, void* d_ws, size_t ws_size,
                              hipStream_t stream){
    const float* x     = (const float*)d_in[0];
    const float* convW = (const float*)d_in[1];
    const float* convb = (const float*)d_in[2];
    const float* bnW   = (const float*)d_in[3];
    const float* bnB   = (const float*)d_in[4];
    const float* bn7W  = (const float*)d_in[5];
    const float* bn7B  = (const float*)d_in[6];
    const float* attW  = (const float*)d_in[7];
    const float* theta = (const float*)d_in[8];
    const float* lin1W = (const float*)d_in[9];
    const float* lin1b = (const float*)d_in[10];
    const float* lin2W = (const float*)d_in[11];
    const float* lin2b = (const float*)d_in[12];
    const float* lin3W = (const float*)d_in[13];
    const float* lin3b = (const float*)d_in[14];
    const int*   src0  = (const int*)d_in[15];
    const int*   dst0  = (const int*)d_in[16];

    char* base = (char*)d_ws;
    size_t off = 0;
    auto take = [&](size_t bytes) -> void* {
        void* p = base + off;
        off = (off + bytes + 255) & ~(size_t)255;
        return p;
    };
    float* bufGP = (float*)take((size_t)N0G*HF*4);
    float* bufHA = (float*)take((size_t)N0G*HF*4);
    float* bufHB = (float*)take((size_t)(N0G/2)*HF*4);
    int2*  csr_p = (int2*) take((size_t)ETOT*8);
    int2*  rb2A  = (int2*) take((size_t)N0G*8);
    int2*  rb2B  = (int2*) take((size_t)N0G*8);
    float* dinvA = (float*)take((size_t)N0G*4);
    float* dinvB = (float*)take((size_t)N0G*4);
    float* s0G   = (float*)take((size_t)N0G*4);
    int*   siG   = (int*)  take((size_t)(N0G/2)*4);
    float* tssG  = (float*)take((size_t)(N0G/2)*4);
    float* st[3];
    st[0] = (float*)take(STSZ*4);
    st[1] = (float*)take(STSZ*4);
    st[2] = (float*)take(STSZ*4);
    float* gacc  = (float*)take((size_t)B_GRAPH*256*4);
    float* t1    = (float*)take((size_t)B_GRAPH*128*4);
    float* t2    = (float*)take((size_t)B_GRAPH*64*4);
    float* statsH= (float*)take(384*4);

    auto coef = [](int kk, float& ca, float& cc){
        double a = 1.0, b = 1.0;
        double c0 = 2.0*kk*(kk+a+b)*(2.0*kk+a+b-2.0);
        double c1 = (2.0*kk+a+b-1.0)*(2.0*kk+a+b)*(2.0*kk+a+b-2.0);
        double c3 = 2.0*(kk+a-1.0)*(kk+b-1.0)*(2.0*kk+a+b);
        ca = (float)(c1/c0); cc = (float)(-c3/c0);
    };
    float ca2, cc2, ca3, cc3;
    coef(2, ca2, cc2);
    coef(3, ca3, cc3);

    k_init_gemm<<<128 + 512, 256, 0, stream>>>(x, convW, bufGP,
                                               src0, dst0, csr_p, rb2A, dinvA,
                                               gacc, statsH, st[0], st[1], st[2]);
    k_prop_lds<512><<<512, 512, 0, stream>>>(bufGP, convb, rb2A, csr_p, dinvA, bufHA, st[0]);

    float* G = bufGP + (size_t)4*1024*1024;   // G region for levels >= 1

    for (int i = 0; i < 5; ++i){
        int n = 512 >> i;
        int kk = n >> 1;
        int Nn = B_GRAPH*n;
        float invN = 1.0f/(float)Nn;
        int2*  rb_cur = (i & 1) ? rb2B : rb2A;
        int2*  rb_nxt = (i & 1) ? rb2A : rb2B;
        float* dv_cur = (i & 1) ? dinvB : dinvA;
        float* dv_nxt = (i & 1) ? dinvA : dinvB;
        float* Hcur = (i & 1) ? bufHB : bufHA;
        float* Hnxt = (i & 1) ? bufHA : bufHB;

        k_score<<<Nn/128, 256, 0, stream>>>(Hcur, st[i % 3], bnW + i*HF, bnB + i*HF, attW + i*HF,
                                            s0G, invN);
        k_pool<<<B_GRAPH, 1024, 0, stream>>>(Hcur, st[i % 3], bnW + i*HF, bnB + i*HF,
                                             theta + i*4, rb_cur, csr_p, dv_cur, s0G,
                                             gacc, rb_nxt, dv_nxt,
                                             st[(i + 1) % 3], siG, tssG,
                                             lin1W, lin1b, t1, statsH,
                                             invN, ca2, cc2, ca3, cc3, n, (i == 4) ? 1 : 0);
        if (i < 4){
            int wnext = i + 1;
            int rows = B_GRAPH * kk;
            int lk = 8 - i;          // log2(kk): 8,7,6,5
            int ln = 9 - i;          // log2(n):  9,8,7,6
            const float* Wn = convW + (size_t)wnext*HF*HF;
            if (i == 0)
                k_gemm_gs<8><<<rows/128, 256, 0, stream>>>(Hcur, st[i % 3], bnW + i*HF, bnB + i*HF,
                                                           siG, tssG, Wn, G, invN, lk, ln);
            else if (i == 1)
                k_gemm_gs<4><<<rows/64, 256, 0, stream>>>(Hcur, st[i % 3], bnW + i*HF, bnB + i*HF,
                                                          siG, tssG, Wn, G, invN, lk, ln);
            else
                k_gemm_g32<<<rows/32, 256, 0, stream>>>(Hcur, st[i % 3], bnW + i*HF, bnB + i*HF,
                                                        siG, tssG, Wn, G, invN, lk, ln);
            if (kk == 256){
                k_prop_lds<256><<<512, 512, 0, stream>>>(G, convb + wnext*HF, rb_nxt, csr_p, dv_nxt,
                                                         Hnxt, st[(i + 1) % 3]);
            } else {
                int lbn = (kk == 128) ? 4 : (kk == 64) ? 3 : 2;
                k_prop_stats<<<rows/8, 256, 0, stream>>>(G, convb + wnext*HF, rb_nxt, csr_p, dv_nxt,
                                                         Hnxt, st[(i + 1) % 3], kk, lbn, rows);
            }
        }
    }

    k_head2<<<B_GRAPH, 128, 0, stream>>>(t1, bnW + 5*HF, bnB + 5*HF, lin2W, lin2b, statsH, t2);
    k_head3<<<B_GRAPH, 64, 0, stream>>>(t2, bn7W, bn7B, lin3W, lin3b, statsH, (float*)d_out);
}

// Round 11
// 407.189 us; speedup vs baseline: 1.0022x; 1.0022x over previous
//
#include <hip/hip_runtime.h>
#include <hip/hip_bf16.h>

#define B_GRAPH 128
#define ETOT    (128*4096)
#define N0G     (128*512)
#define HF      128
// banked stats: [8][256] floats (bank = XCD-ish id) to keep atomics uncontended
#define STSZ    2048

// ---------------- merged: per-graph init (blocks 0..127) + level-0 GEMM (blocks 128..639) ----------------
// GEMM branch: A-tile in LDS (XOR-swizzled, 32KB), W from L2; 16-row x 4-col per thread
// (8 row-groups -> W traffic 512KB/block, half of the 8x8 tiling's 1MB).
union IGSmem {
    float As[128*64];                                    // 32 KB (gemm branch A tile)
    struct { int cnt8[8][512]; int cur[512]; float dvl[512]; int wsum[4]; } ini;   // ~20 KB
};

__global__ __launch_bounds__(256) void k_init_gemm(
    const float* __restrict__ A, const float* __restrict__ Wg, float* __restrict__ C,
    const int* __restrict__ s_in, const int* __restrict__ d_in_,
    int2* __restrict__ csr, int2* __restrict__ rb2, float* __restrict__ dinvv,
    float* __restrict__ gacc, float* __restrict__ statsH,
    float* __restrict__ st0, float* __restrict__ st1, float* __restrict__ st2)
{
    __shared__ IGSmem sm;
    int t = threadIdx.x;
    if (blockIdx.x >= 128){
        // ---- GEMM: 128 rows x 128 cols per block; 16 rows x 4 cols per thread ----
        int tx = t & 31, ty = t >> 5;                     // 32 col-groups x 8 row-groups
        int r0 = (blockIdx.x - 128)*128, c0 = tx*4;
        float acc[16][4];
        #pragma unroll
        for (int j=0;j<16;++j)
            #pragma unroll
            for (int l=0;l<4;++l) acc[j][l] = 0.f;
        for (int kh = 0; kh < 2; ++kh){
            __syncthreads();
            #pragma unroll
            for (int p = 0; p < 8; ++p){                  // stage 128x64 A chunk, coalesced, swizzled
                int idx = p*256 + t;
                int row = idx >> 4, col4 = idx & 15;
                float4 v = *(const float4*)(A + (size_t)(r0+row)*HF + kh*64 + col4*4);
                *(float4*)&sm.As[row*64 + ((col4 ^ ((row>>3)&3))<<2)] = v;
            }
            __syncthreads();
            const float* Wk = Wg + kh*64*HF;
            for (int k4 = 0; k4 < 16; ++k4){
                float4 av[16];
                #pragma unroll
                for (int j=0;j<16;++j){
                    int row = ty*16 + j;
                    int swj = (row >> 3) & 3;
                    av[j] = *(const float4*)&sm.As[row*64 + ((k4 ^ swj)<<2)];
                }
                #pragma unroll
                for (int kk=0; kk<4; ++kk){
                    int kl = k4*4 + kk;
                    float4 w0 = *(const float4*)(Wk + kl*HF + c0);
                    #pragma unroll
                    for (int j=0;j<16;++j){
                        float a = reinterpret_cast<const float*>(&av[j])[kk];
                        acc[j][0] += a*w0.x; acc[j][1] += a*w0.y;
                        acc[j][2] += a*w0.z; acc[j][3] += a*w0.w;
                    }
                }
            }
        }
        #pragma unroll
        for (int j=0;j<16;++j)
            *(float4*)(C + (size_t)(r0+ty*16+j)*HF + c0) = make_float4(acc[j][0],acc[j][1],acc[j][2],acc[j][3]);
    } else {
        int g = blockIdx.x;
        int wid = t >> 5;                      // 32-lane group id: 8 privatized histogram copies
        for (int l = t; l < 4096; l += 256) ((int*)sm.ini.cnt8)[l] = 0;
        gacc[g*256 + t] = 0.f;
        if (g == 0){
            if (t < 256){ statsH[t] = 0.f; if (t < 128) statsH[256+t] = 0.f; }
            for (int i = t; i < STSZ; i += 256){ st0[i] = 0.f; st1[i] = 0.f; st2[i] = 0.f; }
        }
        __syncthreads();
        for (int j = t; j < 4096; j += 256){
            int e = g*4096 + j;
            atomicAdd(&sm.ini.cnt8[wid][d_in_[e] & 511], 1);
        }
        __syncthreads();
        int c0 = 0, c1 = 0;
        #pragma unroll
        for (int w = 0; w < 8; ++w){ c0 += sm.ini.cnt8[w][2*t]; c1 += sm.ini.cnt8[w][2*t+1]; }
        int pairsum = c0 + c1;
        // wave-shuffle inclusive scan over 256 threads (4 waves), 1 barrier
        int lane = t & 63, wv = t >> 6;
        int v = pairsum;
        #pragma unroll
        for (int off = 1; off < 64; off <<= 1){
            int nv = __shfl_up(v, off);
            if (lane >= off) v += nv;
        }
        if (lane == 63) sm.ini.wsum[wv] = v;
        __syncthreads();
        for (int ww = 0; ww < wv; ++ww) v += sm.ini.wsum[ww];
        int begpair = v - pairsum;
        sm.ini.cur[2*t]   = begpair;
        sm.ini.cur[2*t+1] = begpair + c0;
        // stash per-node count in cnt8[0] for the rb2 pass
        sm.ini.cnt8[0][2*t]   = c0;
        sm.ini.cnt8[0][2*t+1] = c1;
        __syncthreads();
        for (int l = t; l < 512; l += 256){
            int cl = sm.ini.cnt8[0][l];
            rb2[g*512 + l] = make_int2(g*4096 + sm.ini.cur[l], cl);
            float dv = rsqrtf((float)cl + 1.f);
            sm.ini.dvl[l] = dv;
            dinvv[g*512 + l] = dv;
        }
        __syncthreads();
        for (int j = t; j < 4096; j += 256){
            int e = g*4096 + j;
            int sg = s_in[e], dl = d_in_[e] & 511;
            int p = atomicAdd(&sm.ini.cur[dl], 1);
            csr[g*4096 + (p & 4095)] = make_int2(sg, __float_as_int(sm.ini.dvl[sg & 511]));
        }
    }
}

// ---------------- LDS-staged prop + BN stats (feature-quarter blocks; NN = nodes/graph) ----------------
template<int NN>
__global__ __launch_bounds__(512) void k_prop_lds(
    const float* __restrict__ Y, const float* __restrict__ cb,
    const int2* __restrict__ rb2, const int2* __restrict__ cp,
    const float* __restrict__ dinv, float* __restrict__ X, float* __restrict__ st)
{
    constexpr int TP = 512 / NN;          // threads per node (1 or 2)
    constexpr int FQ = 8 / TP;            // float4s per thread
    __shared__ float4 ly[NN * 8];         // 64 KB at NN=512, 32 KB at NN=256
    int b = blockIdx.x;
    int g = b >> 2, q = b & 3;
    int t = threadIdx.x;
    const float4* Y4 = (const float4*)Y + (size_t)g*NN*32 + q*8;
    for (int i = t; i < NN*8; i += 512){
        int row = i >> 3, slot = i & 7;
        ly[row*8 + ((slot + row) & 7)] = Y4[(size_t)row*32 + slot];
    }
    __syncthreads();
    int r   = t & (NN - 1);
    int sub = t / NN;
    int S0  = sub * FQ;
    int vg  = g*NN + r;
    float dv = dinv[vg];
    int2 rb = rb2[vg];
    int e0  = (rb.x - g*4096) & 4095;
    int len = min(max(rb.y, 0), 4096 - e0);
    const int2* cpg = cp + g*4096 + e0;
    float4 acc[FQ];
    #pragma unroll
    for (int s = 0; s < FQ; ++s) acc[s] = make_float4(0.f,0.f,0.f,0.f);
    for (int j = 0; j < len; ++j){
        int2 e = cpg[j];
        int c = e.x & (NN - 1);
        float en = __int_as_float(e.y);
        #pragma unroll
        for (int s = 0; s < FQ; ++s){
            float4 h = ly[c*8 + ((S0 + s + c) & 7)];
            acc[s].x += en*h.x; acc[s].y += en*h.y; acc[s].z += en*h.z; acc[s].w += en*h.w;
        }
    }
    const float4* cb4 = (const float4*)cb + q*8;
    float4* X4 = (float4*)X + q*8;
    #pragma unroll
    for (int s = 0; s < FQ; ++s){
        float4 y = ly[r*8 + ((S0 + s + r) & 7)];
        float4 cbv = cb4[S0 + s];
        acc[s].x = y.x*dv*dv + dv*acc[s].x + cbv.x;
        acc[s].y = y.y*dv*dv + dv*acc[s].y + cbv.y;
        acc[s].z = y.z*dv*dv + dv*acc[s].z + cbv.z;
        acc[s].w = y.w*dv*dv + dv*acc[s].w + cbv.w;
        X4[(size_t)vg*32 + S0 + s] = acc[s];
    }
    __syncthreads();
    float* lf = (float*)ly;
    #pragma unroll
    for (int s = 0; s < FQ; ++s) *(float4*)&lf[r*32 + (S0 + s)*4] = acc[s];
    __syncthreads();
    float ssum = 0.f, qsum = 0.f;
    {
        int col = t & 31, grp = t >> 5;
        for (int rr = grp; rr < NN; rr += 16){
            float v = lf[rr*32 + col];
            ssum += v; qsum += v*v;
        }
    }
    __syncthreads();
    lf[t] = ssum; lf[512 + t] = qsum;
    __syncthreads();
    if (t < 64){
        int col = t & 31, half = t >> 5;
        float a = 0.f;
        #pragma unroll
        for (int i = 0; i < 16; ++i) a += lf[half*512 + i*32 + col];
        atomicAdd(&st[(b & 7)*256 + half*128 + q*32 + col], a);
    }
}

// ---------------- chip-wide prop + banked BN stats (small levels, XCD swizzle) ----------------
__global__ __launch_bounds__(256) void k_prop_stats(const float* __restrict__ Y, const float* __restrict__ cb,
                                                    const int2* __restrict__ rb2, const int2* __restrict__ cp,
                                                    const float* __restrict__ dinv,
                                                    float* __restrict__ X, float* __restrict__ st,
                                                    int n, int lb, int Nn){
    __shared__ float rs[1024], rq[1024];
    int xcd = blockIdx.x & 7, c = blockIdx.x >> 3;
    int g = xcd*16 + (c >> lb);
    int m = c & ((1 << lb) - 1);
    int nd = threadIdx.x >> 5;
    int v = g*n + m*8 + nd;
    int f4 = threadIdx.x & 31;
    float dv = dinv[v];
    float4 y = *(const float4*)(Y + (size_t)v*HF + f4*4);
    float4 acc = make_float4(0.f, 0.f, 0.f, 0.f);
    int2 rb = rb2[v];
    int len = min(max(rb.y, 0), 4096);
    int e0 = rb.x, e1 = rb.x + len;
    for (int j = e0; j < e1; ++j){
        int2 e = cp[j];
        int s = e.x & (Nn - 1);
        float en = __int_as_float(e.y);
        float4 h = *(const float4*)(Y + (size_t)s*HF + f4*4);
        acc.x += en*h.x; acc.y += en*h.y; acc.z += en*h.z; acc.w += en*h.w;
    }
    int f = f4*4;
    acc.x = y.x*dv*dv + dv*acc.x + cb[f];
    acc.y = y.y*dv*dv + dv*acc.y + cb[f+1];
    acc.z = y.z*dv*dv + dv*acc.z + cb[f+2];
    acc.w = y.w*dv*dv + dv*acc.w + cb[f+3];
    *(float4*)(X + (size_t)v*HF + f) = acc;
    *(float4*)&rs[nd*HF + f] = acc;
    *(float4*)&rq[nd*HF + f] = make_float4(acc.x*acc.x, acc.y*acc.y, acc.z*acc.z, acc.w*acc.w);
    __syncthreads();
    if (threadIdx.x < 128){
        int tt = threadIdx.x;
        float s = 0.f, q = 0.f;
        #pragma unroll
        for (int j = 0; j < 8; ++j){ s += rs[j*HF + tt]; q += rq[j*HF + tt]; }
        atomicAdd(&st[xcd*256 + tt], s);
        atomicAdd(&st[xcd*256 + 128 + tt], q);
    }
}

// ---------------- chip-wide attention score s0 = relu(bn(h))·aw ----------------
__global__ __launch_bounds__(256) void k_score(
    const float* __restrict__ H, const float* __restrict__ stats,
    const float* __restrict__ gw, const float* __restrict__ gb,
    const float* __restrict__ aw, float* __restrict__ s0G, float invN)
{
    __shared__ float bna[128], bnb[128], awl[128];
    int t = threadIdx.x;
    if (t < 128){
        float s = 0.f, q = 0.f;
        #pragma unroll
        for (int b2 = 0; b2 < 8; ++b2){ s += stats[b2*256 + t]; q += stats[b2*256 + 128 + t]; }
        float mean = s*invN;
        float var  = q*invN - mean*mean;
        float iv   = rsqrtf(var + 1e-5f);
        bna[t] = iv*gw[t];
        bnb[t] = gb[t] - mean*iv*gw[t];
        awl[t] = aw[t];
    }
    __syncthreads();
    int v = blockIdx.x*128 + (t >> 1);
    int h = t & 1;
    const float* hp = H + (size_t)v*HF + h*64;
    float part = 0.f;
    #pragma unroll
    for (int j = 0; j < 16; ++j){
        float4 x = *(const float4*)(hp + j*4);
        int f = h*64 + j*4;
        float4 a4 = *(const float4*)&bna[f];
        float4 b4 = *(const float4*)&bnb[f];
        float4 w4 = *(const float4*)&awl[f];
        part += fmaxf(x.x*a4.x + b4.x, 0.f)*w4.x
              + fmaxf(x.y*a4.y + b4.y, 0.f)*w4.y
              + fmaxf(x.z*a4.z + b4.z, 0.f)*w4.z
              + fmaxf(x.w*a4.w + b4.w, 0.f)*w4.w;
    }
    float oth = __shfl_xor(part, 1);
    if (h == 0) s0G[v] = part + oth;
}

// ---------------- staged gather-GEMM: A rows gathered+BN+ReLU+tanh during stage, W from L2 ----------------
template<int RPT>   // rows per thread (8 -> 128-row tile, 4 -> 64-row tile)
__global__ __launch_bounds__(256) void k_gemm_gs(
    const float* __restrict__ Hsrc, const float* __restrict__ stats,
    const float* __restrict__ gw, const float* __restrict__ gb,
    const int* __restrict__ siG, const float* __restrict__ tssG,
    const float* __restrict__ Wg, float* __restrict__ C,
    float invN, int lk, int ln)
{
    constexpr int RPB = RPT*16;
    constexpr int SH  = (RPT == 8) ? 3 : 2;
    __shared__ float As[RPB*64];
    __shared__ float bna[128], bnb[128];
    int t = threadIdx.x;
    if (t < 128){
        float s = 0.f, q = 0.f;
        #pragma unroll
        for (int b2 = 0; b2 < 8; ++b2){ s += stats[b2*256 + t]; q += stats[b2*256 + 128 + t]; }
        float mean = s*invN;
        float var  = q*invN - mean*mean;
        float iv   = rsqrtf(var + 1e-5f);
        bna[t] = iv*gw[t];
        bnb[t] = gb[t] - mean*iv*gw[t];
    }
    int tx = t & 15, ty = t >> 4;
    int r0 = blockIdx.x*RPB, c0 = tx*4;
    int nmask = (1 << ln) - 1;
    int sw = ty & 3;
    float acc[RPT][8];
    #pragma unroll
    for (int j=0;j<RPT;++j)
        #pragma unroll
        for (int l=0;l<8;++l) acc[j][l] = 0.f;
    for (int kh = 0; kh < 2; ++kh){
        __syncthreads();
        #pragma unroll
        for (int p = 0; p < RPB/16; ++p){
            int idx = p*256 + t;
            int row = idx >> 4, col4 = idx & 15;
            int rg = r0 + row;
            int g = rg >> lk;
            int old = siG[rg] & nmask;
            float ts = tssG[rg];
            int f = kh*64 + col4*4;
            float4 v = *(const float4*)(Hsrc + (size_t)((g<<ln)+old)*HF + f);
            float4 ba = *(const float4*)&bna[f];
            float4 bb = *(const float4*)&bnb[f];
            v.x = fmaxf(v.x*ba.x + bb.x, 0.f)*ts;
            v.y = fmaxf(v.y*ba.y + bb.y, 0.f)*ts;
            v.z = fmaxf(v.z*ba.z + bb.z, 0.f)*ts;
            v.w = fmaxf(v.w*ba.w + bb.w, 0.f)*ts;
            *(float4*)&As[row*64 + ((col4 ^ ((row>>SH)&3))<<2)] = v;
        }
        __syncthreads();
        const float* Wk = Wg + kh*64*HF;
        for (int k4 = 0; k4 < 16; ++k4){
            float4 av[RPT];
            #pragma unroll
            for (int j=0;j<RPT;++j)
                av[j] = *(const float4*)&As[(ty*RPT+j)*64 + ((k4 ^ sw)<<2)];
            #pragma unroll
            for (int kk=0; kk<4; ++kk){
                int kl = k4*4 + kk;
                float4 w0 = *(const float4*)(Wk + kl*HF + c0);
                float4 w1 = *(const float4*)(Wk + kl*HF + c0 + 64);
                #pragma unroll
                for (int j=0;j<RPT;++j){
                    float a = reinterpret_cast<const float*>(&av[j])[kk];
                    acc[j][0] += a*w0.x; acc[j][1] += a*w0.y; acc[j][2] += a*w0.z; acc[j][3] += a*w0.w;
                    acc[j][4] += a*w1.x; acc[j][5] += a*w1.y; acc[j][6] += a*w1.z; acc[j][7] += a*w1.w;
                }
            }
        }
    }
    #pragma unroll
    for (int j=0;j<RPT;++j){
        *(float4*)(C + (size_t)(r0+ty*RPT+j)*HF + c0)      = make_float4(acc[j][0],acc[j][1],acc[j][2],acc[j][3]);
        *(float4*)(C + (size_t)(r0+ty*RPT+j)*HF + c0 + 64) = make_float4(acc[j][4],acc[j][5],acc[j][6],acc[j][7]);
    }
}

// ---------------- small-level gather-GEMM: 32-row tiles, unstaged (max grid parallelism) ----------------
__global__ __launch_bounds__(256) void k_gemm_g32(
    const float* __restrict__ Hsrc, const float* __restrict__ stats,
    const float* __restrict__ gw, const float* __restrict__ gb,
    const int* __restrict__ siG, const float* __restrict__ tssG,
    const float* __restrict__ Wg, float* __restrict__ C,
    float invN, int lk, int ln)
{
    __shared__ float bna[128], bnb[128];
    int t = threadIdx.x;
    if (t < 128){
        float s = 0.f, q = 0.f;
        #pragma unroll
        for (int b2 = 0; b2 < 8; ++b2){ s += stats[b2*256 + t]; q += stats[b2*256 + 128 + t]; }
        float mean = s*invN;
        float var  = q*invN - mean*mean;
        float iv   = rsqrtf(var + 1e-5f);
        bna[t] = iv*gw[t];
        bnb[t] = gb[t] - mean*iv*gw[t];
    }
    __syncthreads();
    int tx = t & 15, ty = t >> 4;
    int r0 = blockIdx.x*32 + ty*2, c0 = tx*4;
    int nmask = (1 << ln) - 1;
    int rbase[2]; float ts_[2];
    #pragma unroll
    for (int j = 0; j < 2; ++j){
        int rg = r0 + j;
        int g = rg >> lk;
        int old = siG[rg] & nmask;
        rbase[j] = ((g << ln) + old) * HF;
        ts_[j] = tssG[rg];
    }
    float acc[2][8];
    #pragma unroll
    for (int j=0;j<2;++j)
        #pragma unroll
        for (int l=0;l<8;++l) acc[j][l] = 0.f;
    for (int k4 = 0; k4 < 32; ++k4){
        int f = k4*4;
        float4 ba = *(const float4*)&bna[f];
        float4 bb = *(const float4*)&bnb[f];
        float4 av[2];
        #pragma unroll
        for (int j=0;j<2;++j){
            av[j] = *(const float4*)(Hsrc + (size_t)rbase[j] + f);
            av[j].x = fmaxf(av[j].x*ba.x + bb.x, 0.f)*ts_[j];
            av[j].y = fmaxf(av[j].y*ba.y + bb.y, 0.f)*ts_[j];
            av[j].z = fmaxf(av[j].z*ba.z + bb.z, 0.f)*ts_[j];
            av[j].w = fmaxf(av[j].w*ba.w + bb.w, 0.f)*ts_[j];
        }
        #pragma unroll
        for (int kk=0; kk<4; ++kk){
            int kl = f + kk;
            float4 w0 = *(const float4*)(Wg + kl*HF + c0);
            float4 w1 = *(const float4*)(Wg + kl*HF + c0 + 64);
            #pragma unroll
            for (int j=0;j<2;++j){
                float a = reinterpret_cast<const float*>(&av[j])[kk];
                acc[j][0] += a*w0.x; acc[j][1] += a*w0.y; acc[j][2] += a*w0.z; acc[j][3] += a*w0.w;
                acc[j][4] += a*w1.x; acc[j][5] += a*w1.y; acc[j][6] += a*w1.z; acc[j][7] += a*w1.w;
            }
        }
    }
    #pragma unroll
    for (int j=0;j<2;++j){
        *(float4*)(C + (size_t)(r0+j)*HF + c0)      = make_float4(acc[j][0],acc[j][1],acc[j][2],acc[j][3]);
        *(float4*)(C + (size_t)(r0+j)*HF + c0 + 64) = make_float4(acc[j][4],acc[j][5],acc[j][6],acc[j][7]);
    }
}

// ---------------- per-graph kernel: pvec/top-k/CSR-rebuild/readout (+head1 at last) ----------------
struct __align__(16) PSmem {
    int2  eds[4096];
    int2  rbl[512];
    float dvv[512], p0[512], p1[512], p2[512];
    float ss[512]; int si[512]; float tss[256]; int nid[512];
    int   cnt_[256]; int wsum[4]; float dvn[256];
    float bna[128], bnb[128]; float red[1024];
};

__global__ __launch_bounds__(1024) void k_pool(
    const float* __restrict__ H, const float* __restrict__ stats,
    const float* __restrict__ gw, const float* __restrict__ gb,
    const float* __restrict__ th,
    const int2* __restrict__ rb2, int2* __restrict__ csr, const float* __restrict__ dinv,
    const float* __restrict__ s0G,
    float* __restrict__ gacc, int2* __restrict__ rb2n, float* __restrict__ dinvn,
    float* __restrict__ stZero, int* __restrict__ siG, float* __restrict__ tssG,
    const float* __restrict__ lin1W, const float* __restrict__ lin1b,
    float* __restrict__ t1g, float* __restrict__ statsH,
    float invN, float ca2, float cc2, float ca3, float cc3,
    int n, int last)
{
    int g = blockIdx.x, t = threadIdx.x;
    int k = n >> 1;
    __shared__ PSmem sm;

    if (t < 256) stZero[(g & 7)*256 + t] = 0.f;
    if (t < 128){
        float s = 0.f, q = 0.f;
        #pragma unroll
        for (int b2 = 0; b2 < 8; ++b2){ s += stats[b2*256 + t]; q += stats[b2*256 + 128 + t]; }
        float mean = s*invN;
        float var  = q*invN - mean*mean;
        float iv   = rsqrtf(var + 1e-5f);
        sm.bna[t] = iv*gw[t];
        sm.bnb[t] = gb[t] - mean*iv*gw[t];
    }
    for (int l = t; l < n; l += 1024){
        int2 rb = rb2[g*n + l];
        int bx = (rb.x - g*4096) & 4095;
        int by = min(max(rb.y, 0), 4096 - bx);
        sm.rbl[l] = make_int2(bx, by);
        sm.dvv[l] = dinv[g*n + l];
        sm.p0[l]  = s0G[g*n + l];
    }
    __syncthreads();
    int medg = sm.rbl[n-1].x + sm.rbl[n-1].y;
    for (int j = t; j < medg; j += 1024){
        int2 e = csr[g*4096 + j];
        sm.eds[j] = make_int2(e.x & (n-1), e.y);
    }
    __syncthreads();
    for (int l = t; l < n; l += 1024){
        int2 rc = sm.rbl[l];
        float acc = 0.f;
        for (int j = 0; j < rc.y; ++j){
            int2 e = sm.eds[rc.x + j];
            acc += __int_as_float(e.y) * sm.p0[e.x];
        }
        float dv = sm.dvv[l];
        sm.p1[l] = 2.f*(sm.p0[l]*dv*dv + dv*acc);
    }
    __syncthreads();
    for (int l = t; l < n; l += 1024){
        int2 rc = sm.rbl[l];
        float acc = 0.f;
        for (int j = 0; j < rc.y; ++j){
            int2 e = sm.eds[rc.x + j];
            acc += __int_as_float(e.y) * sm.p1[e.x];
        }
        float dv = sm.dvv[l];
        sm.p2[l] = ca2*(sm.p1[l]*dv*dv + dv*acc) + cc2*sm.p0[l];
    }
    __syncthreads();
    float t0v = th[0], t1v = th[1], t2c = th[2], t3v = th[3];
    for (int l = t; l < n; l += 1024){
        int2 rc = sm.rbl[l];
        float acc = 0.f;
        for (int j = 0; j < rc.y; ++j){
            int2 e = sm.eds[rc.x + j];
            acc += __int_as_float(e.y) * sm.p2[e.x];
        }
        float dv = sm.dvv[l];
        float tv = sm.p2[l]*dv*dv + dv*acc;
        float p3 = ca3*tv + cc3*sm.p1[l];
        sm.ss[l] = t0v*sm.p0[l] + t1v*sm.p1[l] + t2c*sm.p2[l] + t3v*p3;
    }
    __syncthreads();
    for (int l = t; l < n; l += 1024){
        float sl = sm.ss[l];
        int r = 0;
        for (int j = 0; j < n; j += 4){
            float4 s4 = *(const float4*)&sm.ss[j];
            r += (s4.x > sl) || (s4.x == sl && (j    ) < l);
            r += (s4.y > sl) || (s4.y == sl && (j + 1) < l);
            r += (s4.z > sl) || (s4.z == sl && (j + 2) < l);
            r += (s4.w > sl) || (s4.w == sl && (j + 3) < l);
        }
        if (r < k){
            sm.nid[l] = r;
            sm.si[r]  = l;
            float tv = tanhf(sl);
            sm.tss[r] = tv;
            siG[g*k + r]  = l;
            tssG[g*k + r] = tv;
        } else {
            sm.nid[l] = -1;
        }
    }
    __syncthreads();
    if (!last){
        if (t < k){
            int l = sm.si[t] & (n-1);
            int2 rc = sm.rbl[l];
            int c2 = 0;
            for (int j = 0; j < rc.y; ++j) c2 += (sm.nid[sm.eds[rc.x + j].x] >= 0);
            sm.cnt_[t] = c2;
        }
        __syncthreads();
        int c = (t < 256) ? ((t < k) ? sm.cnt_[t] : 0) : 0;
        int vscan = c;
        if (t < 256){
            int lane = t & 63;
            #pragma unroll
            for (int off = 1; off < 64; off <<= 1){
                int nv = __shfl_up(vscan, off);
                if (lane >= off) vscan += nv;
            }
            if (lane == 63) sm.wsum[t >> 6] = vscan;
        }
        __syncthreads();
        int beg = 0;
        if (t < k){
            int wv = t >> 6;
            int add = 0;
            for (int ww = 0; ww < wv; ++ww) add += sm.wsum[ww];
            vscan += add;
            beg = vscan - c;
            rb2n[g*k + t] = make_int2(g*4096 + beg, c);
            float dv = rsqrtf((float)c + 1.f);
            dinvn[g*k + t] = dv;
            sm.dvn[t] = dv;
        }
        __syncthreads();
        if (t < k){
            int l = sm.si[t] & (n-1);
            int2 rc = sm.rbl[l];
            int p = beg;
            for (int j = 0; j < rc.y; ++j){
                int ns = sm.nid[sm.eds[rc.x + j].x];
                if (ns >= 0){ csr[g*4096 + (p & 4095)] = make_int2(g*k + ns, __float_as_int(sm.dvn[ns])); ++p; }
            }
        }
        __syncthreads();
    }
    {
        int f4 = t & 31, rl = t >> 5;
        int f = f4*4;
        float4 a4 = *(const float4*)&sm.bna[f];
        float4 b4 = *(const float4*)&sm.bnb[f];
        float4 mx = make_float4(-3.4e38f,-3.4e38f,-3.4e38f,-3.4e38f);
        float4 smv = make_float4(0.f,0.f,0.f,0.f);
        for (int r = rl; r < k; r += 32){
            int old = sm.si[r] & (n-1);
            float4 hv = *(const float4*)(H + ((size_t)g*n + old)*HF + f);
            float ts = sm.tss[r];
            float4 v;
            v.x = fmaxf(hv.x*a4.x + b4.x, 0.f)*ts;
            v.y = fmaxf(hv.y*a4.y + b4.y, 0.f)*ts;
            v.z = fmaxf(hv.z*a4.z + b4.z, 0.f)*ts;
            v.w = fmaxf(hv.w*a4.w + b4.w, 0.f)*ts;
            mx.x = fmaxf(mx.x, v.x); mx.y = fmaxf(mx.y, v.y);
            mx.z = fmaxf(mx.z, v.z); mx.w = fmaxf(mx.w, v.w);
            smv.x += v.x; smv.y += v.y; smv.z += v.z; smv.w += v.w;
        }
        float* scr = (float*)sm.eds;
        *(float4*)&scr[rl*128 + f]        = mx;
        *(float4*)&scr[4096 + rl*128 + f] = smv;
        __syncthreads();
        if (t < 128){
            float m = -3.4e38f, s = 0.f;
            #pragma unroll
            for (int j = 0; j < 32; ++j){
                m = fmaxf(m, scr[j*128 + t]);
                s += scr[4096 + j*128 + t];
            }
            gacc[g*256 + t] += m;
            gacc[g*256 + 128 + t] += s / (float)k;
        }
    }
    if (last){
        __syncthreads();
        int c = t & 127, h = t >> 7;
        float s = 0.f;
        int k0 = h*32;
        #pragma unroll
        for (int kk = 0; kk < 32; ++kk)
            s += gacc[g*256 + k0 + kk] * lin1W[(k0 + kk)*128 + c];
        sm.red[t] = s;
        __syncthreads();
        if (t < 512) sm.red[t] += sm.red[t+512];
        __syncthreads();
        if (t < 256) sm.red[t] += sm.red[t+256];
        __syncthreads();
        if (t < 128){
            float v = (sm.red[t] + sm.red[t+128]) * 0.2f + lin1b[t];
            t1g[g*128 + t] = v;
            atomicAdd(&statsH[t], v);
            atomicAdd(&statsH[128+t], v*v);
        }
    }
}

// ---------------- head tail kernels ----------------
__global__ __launch_bounds__(128) void k_head2(const float* __restrict__ t1, const float* __restrict__ gw,
                                               const float* __restrict__ gb, const float* __restrict__ W2,
                                               const float* __restrict__ b2, float* __restrict__ sh,
                                               float* __restrict__ t2){
    int r = blockIdx.x, t = threadIdx.x;
    int cc = t & 63, h = t >> 6;
    __shared__ float row[128];
    __shared__ float red[128];
    {
        float mean = sh[t] * (1.f/128.f);
        float var  = sh[128+t]*(1.f/128.f) - mean*mean;
        float iv   = rsqrtf(var + 1e-5f);
        float v = (t1[r*128+t] - mean)*iv*gw[t] + gb[t];
        row[t] = fmaxf(v, 0.f);
    }
    __syncthreads();
    float s = 0.f;
    #pragma unroll
    for (int kk = 0; kk < 64; ++kk)
        s += row[h*64+kk] * W2[(h*64+kk)*64 + cc];
    red[t] = s;
    __syncthreads();
    if (h == 0){
        float v = red[cc] + red[cc+64] + b2[cc];
        t2[r*64+cc] = v;
        atomicAdd(&sh[256+cc], v);
        atomicAdd(&sh[320+cc], v*v);
    }
}
__global__ __launch_bounds__(64) void k_head3(const float* __restrict__ t2, const float* __restrict__ gw,
                                              const float* __restrict__ gb, const float* __restrict__ W3,
                                              const float* __restrict__ b3, const float* __restrict__ sh,
                                              float* __restrict__ out){
    int r = blockIdx.x, t = threadIdx.x;
    float mean = sh[256+t]*(1.f/128.f);
    float var  = sh[320+t]*(1.f/128.f) - mean*mean;
    float iv   = rsqrtf(var + 1e-5f);
    float v = fmaxf((t2[r*64+t]-mean)*iv*gw[t] + gb[t], 0.f);
    float lg[10];
    #pragma unroll
    for (int j = 0; j < 10; ++j){
        float p = v * W3[t*10 + j];
        for (int off = 32; off; off >>= 1) p += __shfl_down(p, off);
        lg[j] = p;
    }
    if (t == 0){
        float m = -3.4e38f;
        #pragma unroll
        for (int j = 0; j < 10; ++j){ lg[j] += b3[j]; m = fmaxf(m, lg[j]); }
        float se = 0.f;
        #pragma unroll
        for (int j = 0; j < 10; ++j) se += expf(lg[j] - m);
        float l = logf(se) + m;
        #pragma unroll
        for (int j = 0; j < 10; ++j) out[r*10 + j] = lg[j] - l;
    }
}

extern "C" void kernel_launch(void* const* d_in, const int* in_sizes, int n_in,
                              void* d_out, int out_size, void* d_ws, size_t ws_size,
                              hipStream_t stream){
    const float* x     = (const float*)d_in[0];
    const float* convW = (const float*)d_in[1];
    const float* convb = (const float*)d_in[2];
    const float* bnW   = (const float*)d_in[3];
    const float* bnB   = (const float*)d_in[4];
    const float* bn7W  = (const float*)d_in[5];
    const float* bn7B  = (const float*)d_in[6];
    const float* attW  = (const float*)d_in[7];
    const float* theta = (const float*)d_in[8];
    const float* lin1W = (const float*)d_in[9];
    const float* lin1b = (const float*)d_in[10];
    const float* lin2W = (const float*)d_in[11];
    const float* lin2b = (const float*)d_in[12];
    const float* lin3W = (const float*)d_in[13];
    const float* lin3b = (const float*)d_in[14];
    const int*   src0  = (const int*)d_in[15];
    const int*   dst0  = (const int*)d_in[16];

    char* base = (char*)d_ws;
    size_t off = 0;
    auto take = [&](size_t bytes) -> void* {
        void* p = base + off;
        off = (off + bytes + 255) & ~(size_t)255;
        return p;
    };
    float* bufGP = (float*)take((size_t)N0G*HF*4);
    float* bufHA = (float*)take((size_t)N0G*HF*4);
    float* bufHB = (float*)take((size_t)(N0G/2)*HF*4);
    int2*  csr_p = (int2*) take((size_t)ETOT*8);
    int2*  rb2A  = (int2*) take((size_t)N0G*8);
    int2*  rb2B  = (int2*) take((size_t)N0G*8);
    float* dinvA = (float*)take((size_t)N0G*4);
    float* dinvB = (float*)take((size_t)N0G*4);
    float* s0G   = (float*)take((size_t)N0G*4);
    int*   siG   = (int*)  take((size_t)(N0G/2)*4);
    float* tssG  = (float*)take((size_t)(N0G/2)*4);
    float* st[3];
    st[0] = (float*)take(STSZ*4);
    st[1] = (float*)take(STSZ*4);
    st[2] = (float*)take(STSZ*4);
    float* gacc  = (float*)take((size_t)B_GRAPH*256*4);
    float* t1    = (float*)take((size_t)B_GRAPH*128*4);
    float* t2    = (float*)take((size_t)B_GRAPH*64*4);
    float* statsH= (float*)take(384*4);

    auto coef = [](int kk, float& ca, float& cc){
        double a = 1.0, b = 1.0;
        double c0 = 2.0*kk*(kk+a+b)*(2.0*kk+a+b-2.0);
        double c1 = (2.0*kk+a+b-1.0)*(2.0*kk+a+b)*(2.0*kk+a+b-2.0);
        double c3 = 2.0*(kk+a-1.0)*(kk+b-1.0)*(2.0*kk+a+b);
        ca = (float)(c1/c0); cc = (float)(-c3/c0);
    };
    float ca2, cc2, ca3, cc3;
    coef(2, ca2, cc2);
    coef(3, ca3, cc3);

    k_init_gemm<<<128 + 512, 256, 0, stream>>>(x, convW, bufGP,
                                               src0, dst0, csr_p, rb2A, dinvA,
                                               gacc, statsH, st[0], st[1], st[2]);
    k_prop_lds<512><<<512, 512, 0, stream>>>(bufGP, convb, rb2A, csr_p, dinvA, bufHA, st[0]);

    float* G = bufGP + (size_t)4*1024*1024;   // G region for levels >= 1

    for (int i = 0; i < 5; ++i){
        int n = 512 >> i;
        int kk = n >> 1;
        int Nn = B_GRAPH*n;
        float invN = 1.0f/(float)Nn;
        int2*  rb_cur = (i & 1) ? rb2B : rb2A;
        int2*  rb_nxt = (i & 1) ? rb2A : rb2B;
        float* dv_cur = (i & 1) ? dinvB : dinvA;
        float* dv_nxt = (i & 1) ? dinvA : dinvB;
        float* Hcur = (i & 1) ? bufHB : bufHA;
        float* Hnxt = (i & 1) ? bufHA : bufHB;

        k_score<<<Nn/128, 256, 0, stream>>>(Hcur, st[i % 3], bnW + i*HF, bnB + i*HF, attW + i*HF,
                                            s0G, invN);
        k_pool<<<B_GRAPH, 1024, 0, stream>>>(Hcur, st[i % 3], bnW + i*HF, bnB + i*HF,
                                             theta + i*4, rb_cur, csr_p, dv_cur, s0G,
                                             gacc, rb_nxt, dv_nxt,
                                             st[(i + 1) % 3], siG, tssG,
                                             lin1W, lin1b, t1, statsH,
                                             invN, ca2, cc2, ca3, cc3, n, (i == 4) ? 1 : 0);
        if (i < 4){
            int wnext = i + 1;
            int rows = B_GRAPH * kk;
            int lk = 8 - i;          // log2(kk): 8,7,6,5
            int ln = 9 - i;          // log2(n):  9,8,7,6
            const float* Wn = convW + (size_t)wnext*HF*HF;
            if (i == 0)
                k_gemm_gs<8><<<rows/128, 256, 0, stream>>>(Hcur, st[i % 3], bnW + i*HF, bnB + i*HF,
                                                           siG, tssG, Wn, G, invN, lk, ln);
            else if (i == 1)
                k_gemm_gs<4><<<rows/64, 256, 0, stream>>>(Hcur, st[i % 3], bnW + i*HF, bnB + i*HF,
                                                          siG, tssG, Wn, G, invN, lk, ln);
            else
                k_gemm_g32<<<rows/32, 256, 0, stream>>>(Hcur, st[i % 3], bnW + i*HF, bnB + i*HF,
                                                        siG, tssG, Wn, G, invN, lk, ln);
            if (kk == 256){
                k_prop_lds<256><<<512, 512, 0, stream>>>(G, convb + wnext*HF, rb_nxt, csr_p, dv_nxt,
                                                         Hnxt, st[(i + 1) % 3]);
            } else {
                int lbn = (kk == 128) ? 4 : (kk == 64) ? 3 : 2;
                k_prop_stats<<<rows/8, 256, 0, stream>>>(G, convb + wnext*HF, rb_nxt, csr_p, dv_nxt,
                                                         Hnxt, st[(i + 1) % 3], kk, lbn, rows);
            }
        }
    }

    k_head2<<<B_GRAPH, 128, 0, stream>>>(t1, bnW + 5*HF, bnB + 5*HF, lin2W, lin2b, statsH, t2);
    k_head3<<<B_GRAPH, 64, 0, stream>>>(t2, bn7W, bn7B, lin3W, lin3b, statsH, (float*)d_out);
}

// Round 12
// 392.022 us; speedup vs baseline: 1.0410x; 1.0387x over previous
//
#include <hip/hip_runtime.h>
#include <hip/hip_bf16.h>

#define B_GRAPH 128
#define ETOT    (128*4096)
#define N0G     (128*512)
#define HF      128
// banked stats: [8][256] floats (bank = XCD-ish id) to keep atomics uncontended
#define STSZ    2048

// ---------------- merged: per-graph init (blocks 0..127) + level-0 GEMM (blocks 128..639) ----------------
// GEMM branch (r8 champion): A-tile in LDS (XOR-swizzled, 32KB), W from L2, 8x8 per thread.
union IGSmem {
    float As[128*64];                                    // 32 KB (gemm branch A tile)
    struct { int cnt8[8][512]; int cur[512]; float dvl[512]; int wsum[4]; } ini;   // ~20 KB
};

__global__ __launch_bounds__(256) void k_init_gemm(
    const float* __restrict__ A, const float* __restrict__ Wg, float* __restrict__ C,
    const int* __restrict__ s_in, const int* __restrict__ d_in_,
    int2* __restrict__ csr, int2* __restrict__ rb2, float* __restrict__ dinvv,
    float* __restrict__ gacc, float* __restrict__ statsH,
    float* __restrict__ st0, float* __restrict__ st1, float* __restrict__ st2)
{
    __shared__ IGSmem sm;
    int t = threadIdx.x;
    if (blockIdx.x >= 128){
        // ---- GEMM: 128 rows x 128 cols per block, 8x8 per thread ----
        int tx = t & 15, ty = t >> 4;
        int r0 = (blockIdx.x - 128)*128, c0 = tx*4;
        int sw = ty & 3;                                  // read-side swizzle key
        float acc[8][8];
        #pragma unroll
        for (int j=0;j<8;++j)
            #pragma unroll
            for (int l=0;l<8;++l) acc[j][l] = 0.f;
        for (int kh = 0; kh < 2; ++kh){
            __syncthreads();
            #pragma unroll
            for (int p = 0; p < 8; ++p){                  // stage 128x64 A chunk, coalesced, swizzled
                int idx = p*256 + t;
                int row = idx >> 4, col4 = idx & 15;
                float4 v = *(const float4*)(A + (size_t)(r0+row)*HF + kh*64 + col4*4);
                *(float4*)&sm.As[row*64 + ((col4 ^ ((row>>3)&3))<<2)] = v;
            }
            __syncthreads();
            const float* Wk = Wg + kh*64*HF;
            for (int k4 = 0; k4 < 16; ++k4){
                float4 av[8];
                #pragma unroll
                for (int j=0;j<8;++j)
                    av[j] = *(const float4*)&sm.As[(ty*8+j)*64 + ((k4 ^ sw)<<2)];
                #pragma unroll
                for (int kk=0; kk<4; ++kk){
                    int kl = k4*4 + kk;
                    float4 w0 = *(const float4*)(Wk + kl*HF + c0);
                    float4 w1 = *(const float4*)(Wk + kl*HF + c0 + 64);
                    #pragma unroll
                    for (int j=0;j<8;++j){
                        float a = reinterpret_cast<const float*>(&av[j])[kk];
                        acc[j][0] += a*w0.x; acc[j][1] += a*w0.y; acc[j][2] += a*w0.z; acc[j][3] += a*w0.w;
                        acc[j][4] += a*w1.x; acc[j][5] += a*w1.y; acc[j][6] += a*w1.z; acc[j][7] += a*w1.w;
                    }
                }
            }
        }
        #pragma unroll
        for (int j=0;j<8;++j){
            *(float4*)(C + (size_t)(r0+ty*8+j)*HF + c0)      = make_float4(acc[j][0],acc[j][1],acc[j][2],acc[j][3]);
            *(float4*)(C + (size_t)(r0+ty*8+j)*HF + c0 + 64) = make_float4(acc[j][4],acc[j][5],acc[j][6],acc[j][7]);
        }
    } else {
        int g = blockIdx.x;
        int wid = t >> 5;                      // 32-lane group id: 8 privatized histogram copies
        for (int l = t; l < 4096; l += 256) ((int*)sm.ini.cnt8)[l] = 0;
        gacc[g*256 + t] = 0.f;
        if (g == 0){
            if (t < 256){ statsH[t] = 0.f; if (t < 128) statsH[256+t] = 0.f; }
            for (int i = t; i < STSZ; i += 256){ st0[i] = 0.f; st1[i] = 0.f; st2[i] = 0.f; }
        }
        __syncthreads();
        for (int j = t; j < 4096; j += 256){
            int e = g*4096 + j;
            atomicAdd(&sm.ini.cnt8[wid][d_in_[e] & 511], 1);
        }
        __syncthreads();
        int c0 = 0, c1 = 0;
        #pragma unroll
        for (int w = 0; w < 8; ++w){ c0 += sm.ini.cnt8[w][2*t]; c1 += sm.ini.cnt8[w][2*t+1]; }
        int pairsum = c0 + c1;
        // wave-shuffle inclusive scan over 256 threads (4 waves), 1 barrier
        int lane = t & 63, wv = t >> 6;
        int v = pairsum;
        #pragma unroll
        for (int off = 1; off < 64; off <<= 1){
            int nv = __shfl_up(v, off);
            if (lane >= off) v += nv;
        }
        if (lane == 63) sm.ini.wsum[wv] = v;
        __syncthreads();
        for (int ww = 0; ww < wv; ++ww) v += sm.ini.wsum[ww];
        int begpair = v - pairsum;
        sm.ini.cur[2*t]   = begpair;
        sm.ini.cur[2*t+1] = begpair + c0;
        // stash per-node count in cnt8[0] for the rb2 pass
        sm.ini.cnt8[0][2*t]   = c0;
        sm.ini.cnt8[0][2*t+1] = c1;
        __syncthreads();
        for (int l = t; l < 512; l += 256){
            int cl = sm.ini.cnt8[0][l];
            rb2[g*512 + l] = make_int2(g*4096 + sm.ini.cur[l], cl);
            float dv = rsqrtf((float)cl + 1.f);
            sm.ini.dvl[l] = dv;
            dinvv[g*512 + l] = dv;
        }
        __syncthreads();
        for (int j = t; j < 4096; j += 256){
            int e = g*4096 + j;
            int sg = s_in[e], dl = d_in_[e] & 511;
            int p = atomicAdd(&sm.ini.cur[dl], 1);
            csr[g*4096 + (p & 4095)] = make_int2(sg, __float_as_int(sm.ini.dvl[sg & 511]));
        }
    }
}

// ---------------- LDS-staged prop + BN stats (feature-quarter blocks; NN = nodes/graph) ----------------
template<int NN>
__global__ __launch_bounds__(512) void k_prop_lds(
    const float* __restrict__ Y, const float* __restrict__ cb,
    const int2* __restrict__ rb2, const int2* __restrict__ cp,
    const float* __restrict__ dinv, float* __restrict__ X, float* __restrict__ st)
{
    constexpr int TP = 512 / NN;          // threads per node (1 or 2)
    constexpr int FQ = 8 / TP;            // float4s per thread
    __shared__ float4 ly[NN * 8];         // 64 KB at NN=512, 32 KB at NN=256
    int b = blockIdx.x;
    int g = b >> 2, q = b & 3;
    int t = threadIdx.x;
    const float4* Y4 = (const float4*)Y + (size_t)g*NN*32 + q*8;
    for (int i = t; i < NN*8; i += 512){
        int row = i >> 3, slot = i & 7;
        ly[row*8 + ((slot + row) & 7)] = Y4[(size_t)row*32 + slot];
    }
    __syncthreads();
    int r   = t & (NN - 1);
    int sub = t / NN;
    int S0  = sub * FQ;
    int vg  = g*NN + r;
    float dv = dinv[vg];
    int2 rb = rb2[vg];
    int e0  = (rb.x - g*4096) & 4095;
    int len = min(max(rb.y, 0), 4096 - e0);
    const int2* cpg = cp + g*4096 + e0;
    float4 acc[FQ];
    #pragma unroll
    for (int s = 0; s < FQ; ++s) acc[s] = make_float4(0.f,0.f,0.f,0.f);
    for (int j = 0; j < len; ++j){
        int2 e = cpg[j];
        int c = e.x & (NN - 1);
        float en = __int_as_float(e.y);
        #pragma unroll
        for (int s = 0; s < FQ; ++s){
            float4 h = ly[c*8 + ((S0 + s + c) & 7)];
            acc[s].x += en*h.x; acc[s].y += en*h.y; acc[s].z += en*h.z; acc[s].w += en*h.w;
        }
    }
    const float4* cb4 = (const float4*)cb + q*8;
    float4* X4 = (float4*)X + q*8;
    #pragma unroll
    for (int s = 0; s < FQ; ++s){
        float4 y = ly[r*8 + ((S0 + s + r) & 7)];
        float4 cbv = cb4[S0 + s];
        acc[s].x = y.x*dv*dv + dv*acc[s].x + cbv.x;
        acc[s].y = y.y*dv*dv + dv*acc[s].y + cbv.y;
        acc[s].z = y.z*dv*dv + dv*acc[s].z + cbv.z;
        acc[s].w = y.w*dv*dv + dv*acc[s].w + cbv.w;
        X4[(size_t)vg*32 + S0 + s] = acc[s];
    }
    __syncthreads();
    float* lf = (float*)ly;
    #pragma unroll
    for (int s = 0; s < FQ; ++s) *(float4*)&lf[r*32 + (S0 + s)*4] = acc[s];
    __syncthreads();
    float ssum = 0.f, qsum = 0.f;
    {
        int col = t & 31, grp = t >> 5;
        for (int rr = grp; rr < NN; rr += 16){
            float v = lf[rr*32 + col];
            ssum += v; qsum += v*v;
        }
    }
    __syncthreads();
    lf[t] = ssum; lf[512 + t] = qsum;
    __syncthreads();
    if (t < 64){
        int col = t & 31, half = t >> 5;
        float a = 0.f;
        #pragma unroll
        for (int i = 0; i < 16; ++i) a += lf[half*512 + i*32 + col];
        atomicAdd(&st[(b & 7)*256 + half*128 + q*32 + col], a);
    }
}

// ---------------- chip-wide prop + banked BN stats (small levels, XCD swizzle) ----------------
__global__ __launch_bounds__(256) void k_prop_stats(const float* __restrict__ Y, const float* __restrict__ cb,
                                                    const int2* __restrict__ rb2, const int2* __restrict__ cp,
                                                    const float* __restrict__ dinv,
                                                    float* __restrict__ X, float* __restrict__ st,
                                                    int n, int lb, int Nn){
    __shared__ float rs[1024], rq[1024];
    int xcd = blockIdx.x & 7, c = blockIdx.x >> 3;
    int g = xcd*16 + (c >> lb);
    int m = c & ((1 << lb) - 1);
    int nd = threadIdx.x >> 5;
    int v = g*n + m*8 + nd;
    int f4 = threadIdx.x & 31;
    float dv = dinv[v];
    float4 y = *(const float4*)(Y + (size_t)v*HF + f4*4);
    float4 acc = make_float4(0.f, 0.f, 0.f, 0.f);
    int2 rb = rb2[v];
    int len = min(max(rb.y, 0), 4096);
    int e0 = rb.x, e1 = rb.x + len;
    for (int j = e0; j < e1; ++j){
        int2 e = cp[j];
        int s = e.x & (Nn - 1);
        float en = __int_as_float(e.y);
        float4 h = *(const float4*)(Y + (size_t)s*HF + f4*4);
        acc.x += en*h.x; acc.y += en*h.y; acc.z += en*h.z; acc.w += en*h.w;
    }
    int f = f4*4;
    acc.x = y.x*dv*dv + dv*acc.x + cb[f];
    acc.y = y.y*dv*dv + dv*acc.y + cb[f+1];
    acc.z = y.z*dv*dv + dv*acc.z + cb[f+2];
    acc.w = y.w*dv*dv + dv*acc.w + cb[f+3];
    *(float4*)(X + (size_t)v*HF + f) = acc;
    *(float4*)&rs[nd*HF + f] = acc;
    *(float4*)&rq[nd*HF + f] = make_float4(acc.x*acc.x, acc.y*acc.y, acc.z*acc.z, acc.w*acc.w);
    __syncthreads();
    if (threadIdx.x < 128){
        int tt = threadIdx.x;
        float s = 0.f, q = 0.f;
        #pragma unroll
        for (int j = 0; j < 8; ++j){ s += rs[j*HF + tt]; q += rq[j*HF + tt]; }
        atomicAdd(&st[xcd*256 + tt], s);
        atomicAdd(&st[xcd*256 + 128 + tt], q);
    }
}

// ---------------- staged gather-GEMM: A rows gathered+BN+ReLU+tanh during stage, W from L2 ----------------
template<int RPT>   // rows per thread (8 -> 128-row tile, 4 -> 64-row tile)
__global__ __launch_bounds__(256) void k_gemm_gs(
    const float* __restrict__ Hsrc, const float* __restrict__ stats,
    const float* __restrict__ gw, const float* __restrict__ gb,
    const int* __restrict__ siG, const float* __restrict__ tssG,
    const float* __restrict__ Wg, float* __restrict__ C,
    float invN, int lk, int ln)
{
    constexpr int RPB = RPT*16;
    constexpr int SH  = (RPT == 8) ? 3 : 2;
    __shared__ float As[RPB*64];
    __shared__ float bna[128], bnb[128];
    int t = threadIdx.x;
    if (t < 128){
        float s = 0.f, q = 0.f;
        #pragma unroll
        for (int b2 = 0; b2 < 8; ++b2){ s += stats[b2*256 + t]; q += stats[b2*256 + 128 + t]; }
        float mean = s*invN;
        float var  = q*invN - mean*mean;
        float iv   = rsqrtf(var + 1e-5f);
        bna[t] = iv*gw[t];
        bnb[t] = gb[t] - mean*iv*gw[t];
    }
    int tx = t & 15, ty = t >> 4;
    int r0 = blockIdx.x*RPB, c0 = tx*4;
    int nmask = (1 << ln) - 1;
    int sw = ty & 3;
    float acc[RPT][8];
    #pragma unroll
    for (int j=0;j<RPT;++j)
        #pragma unroll
        for (int l=0;l<8;++l) acc[j][l] = 0.f;
    for (int kh = 0; kh < 2; ++kh){
        __syncthreads();
        #pragma unroll
        for (int p = 0; p < RPB/16; ++p){
            int idx = p*256 + t;
            int row = idx >> 4, col4 = idx & 15;
            int rg = r0 + row;
            int g = rg >> lk;
            int old = siG[rg] & nmask;
            float ts = tssG[rg];
            int f = kh*64 + col4*4;
            float4 v = *(const float4*)(Hsrc + (size_t)((g<<ln)+old)*HF + f);
            float4 ba = *(const float4*)&bna[f];
            float4 bb = *(const float4*)&bnb[f];
            v.x = fmaxf(v.x*ba.x + bb.x, 0.f)*ts;
            v.y = fmaxf(v.y*ba.y + bb.y, 0.f)*ts;
            v.z = fmaxf(v.z*ba.z + bb.z, 0.f)*ts;
            v.w = fmaxf(v.w*ba.w + bb.w, 0.f)*ts;
            *(float4*)&As[row*64 + ((col4 ^ ((row>>SH)&3))<<2)] = v;
        }
        __syncthreads();
        const float* Wk = Wg + kh*64*HF;
        for (int k4 = 0; k4 < 16; ++k4){
            float4 av[RPT];
            #pragma unroll
            for (int j=0;j<RPT;++j)
                av[j] = *(const float4*)&As[(ty*RPT+j)*64 + ((k4 ^ sw)<<2)];
            #pragma unroll
            for (int kk=0; kk<4; ++kk){
                int kl = k4*4 + kk;
                float4 w0 = *(const float4*)(Wk + kl*HF + c0);
                float4 w1 = *(const float4*)(Wk + kl*HF + c0 + 64);
                #pragma unroll
                for (int j=0;j<RPT;++j){
                    float a = reinterpret_cast<const float*>(&av[j])[kk];
                    acc[j][0] += a*w0.x; acc[j][1] += a*w0.y; acc[j][2] += a*w0.z; acc[j][3] += a*w0.w;
                    acc[j][4] += a*w1.x; acc[j][5] += a*w1.y; acc[j][6] += a*w1.z; acc[j][7] += a*w1.w;
                }
            }
        }
    }
    #pragma unroll
    for (int j=0;j<RPT;++j){
        *(float4*)(C + (size_t)(r0+ty*RPT+j)*HF + c0)      = make_float4(acc[j][0],acc[j][1],acc[j][2],acc[j][3]);
        *(float4*)(C + (size_t)(r0+ty*RPT+j)*HF + c0 + 64) = make_float4(acc[j][4],acc[j][5],acc[j][6],acc[j][7]);
    }
}

// ---------------- small-level gather-GEMM: 32-row tiles, unstaged (max grid parallelism) ----------------
__global__ __launch_bounds__(256) void k_gemm_g32(
    const float* __restrict__ Hsrc, const float* __restrict__ stats,
    const float* __restrict__ gw, const float* __restrict__ gb,
    const int* __restrict__ siG, const float* __restrict__ tssG,
    const float* __restrict__ Wg, float* __restrict__ C,
    float invN, int lk, int ln)
{
    __shared__ float bna[128], bnb[128];
    int t = threadIdx.x;
    if (t < 128){
        float s = 0.f, q = 0.f;
        #pragma unroll
        for (int b2 = 0; b2 < 8; ++b2){ s += stats[b2*256 + t]; q += stats[b2*256 + 128 + t]; }
        float mean = s*invN;
        float var  = q*invN - mean*mean;
        float iv   = rsqrtf(var + 1e-5f);
        bna[t] = iv*gw[t];
        bnb[t] = gb[t] - mean*iv*gw[t];
    }
    __syncthreads();
    int tx = t & 15, ty = t >> 4;
    int r0 = blockIdx.x*32 + ty*2, c0 = tx*4;
    int nmask = (1 << ln) - 1;
    int rbase[2]; float ts_[2];
    #pragma unroll
    for (int j = 0; j < 2; ++j){
        int rg = r0 + j;
        int g = rg >> lk;
        int old = siG[rg] & nmask;
        rbase[j] = ((g << ln) + old) * HF;
        ts_[j] = tssG[rg];
    }
    float acc[2][8];
    #pragma unroll
    for (int j=0;j<2;++j)
        #pragma unroll
        for (int l=0;l<8;++l) acc[j][l] = 0.f;
    for (int k4 = 0; k4 < 32; ++k4){
        int f = k4*4;
        float4 ba = *(const float4*)&bna[f];
        float4 bb = *(const float4*)&bnb[f];
        float4 av[2];
        #pragma unroll
        for (int j=0;j<2;++j){
            av[j] = *(const float4*)(Hsrc + (size_t)rbase[j] + f);
            av[j].x = fmaxf(av[j].x*ba.x + bb.x, 0.f)*ts_[j];
            av[j].y = fmaxf(av[j].y*ba.y + bb.y, 0.f)*ts_[j];
            av[j].z = fmaxf(av[j].z*ba.z + bb.z, 0.f)*ts_[j];
            av[j].w = fmaxf(av[j].w*ba.w + bb.w, 0.f)*ts_[j];
        }
        #pragma unroll
        for (int kk=0; kk<4; ++kk){
            int kl = f + kk;
            float4 w0 = *(const float4*)(Wg + kl*HF + c0);
            float4 w1 = *(const float4*)(Wg + kl*HF + c0 + 64);
            #pragma unroll
            for (int j=0;j<2;++j){
                float a = reinterpret_cast<const float*>(&av[j])[kk];
                acc[j][0] += a*w0.x; acc[j][1] += a*w0.y; acc[j][2] += a*w0.z; acc[j][3] += a*w0.w;
                acc[j][4] += a*w1.x; acc[j][5] += a*w1.y; acc[j][6] += a*w1.z; acc[j][7] += a*w1.w;
            }
        }
    }
    #pragma unroll
    for (int j=0;j<2;++j){
        *(float4*)(C + (size_t)(r0+j)*HF + c0)      = make_float4(acc[j][0],acc[j][1],acc[j][2],acc[j][3]);
        *(float4*)(C + (size_t)(r0+j)*HF + c0 + 64) = make_float4(acc[j][4],acc[j][5],acc[j][6],acc[j][7]);
    }
}

// ---------------- per-graph kernel: s0/pvec/top-k/CSR-rebuild/readout (+head1 at last) ----------------
struct __align__(16) PSmem {
    int2  eds[4096];
    int2  rbl[512];
    float dvv[512], p0[512], p1[512], p2[512];
    float ss[512]; int si[512]; float tss[256]; int nid[512];
    int   cnt_[256]; int wsum[4]; float dvn[256];
    float bna[128], bnb[128], awl[128]; float red[1024];
};

__global__ __launch_bounds__(1024) void k_pool(
    const float* __restrict__ H, const float* __restrict__ stats,
    const float* __restrict__ gw, const float* __restrict__ gb,
    const float* __restrict__ aw, const float* __restrict__ th,
    const int2* __restrict__ rb2, int2* __restrict__ csr, const float* __restrict__ dinv,
    float* __restrict__ gacc, int2* __restrict__ rb2n, float* __restrict__ dinvn,
    float* __restrict__ stZero, int* __restrict__ siG, float* __restrict__ tssG,
    const float* __restrict__ lin1W, const float* __restrict__ lin1b,
    float* __restrict__ t1g, float* __restrict__ statsH,
    float invN, float ca2, float cc2, float ca3, float cc3,
    int n, int last)
{
    int g = blockIdx.x, t = threadIdx.x;
    int k = n >> 1;
    __shared__ PSmem sm;

    if (t < 256) stZero[(g & 7)*256 + t] = 0.f;
    if (t < 128){
        float s = 0.f, q = 0.f;
        #pragma unroll
        for (int b2 = 0; b2 < 8; ++b2){ s += stats[b2*256 + t]; q += stats[b2*256 + 128 + t]; }
        float mean = s*invN;
        float var  = q*invN - mean*mean;
        float iv   = rsqrtf(var + 1e-5f);
        sm.bna[t] = iv*gw[t];
        sm.bnb[t] = gb[t] - mean*iv*gw[t];
        sm.awl[t] = aw[t];
    }
    for (int l = t; l < n; l += 1024){
        int2 rb = rb2[g*n + l];
        int bx = (rb.x - g*4096) & 4095;
        int by = min(max(rb.y, 0), 4096 - bx);
        sm.rbl[l] = make_int2(bx, by);
        sm.dvv[l] = dinv[g*n + l];
    }
    __syncthreads();
    int medg = sm.rbl[n-1].x + sm.rbl[n-1].y;
    for (int j = t; j < medg; j += 1024){
        int2 e = csr[g*4096 + j];
        sm.eds[j] = make_int2(e.x & (n-1), e.y);
    }
    // ---- s0 = relu(bn(h))·aw : 2 threads/node, float4 (bit-identical to old k_score order) ----
    {
        int l = t >> 1, h = t & 1;
        float part = 0.f;
        if (l < n){
            const float* hp = H + ((size_t)g*n + l)*HF + h*64;
            #pragma unroll
            for (int j = 0; j < 16; ++j){
                float4 v = *(const float4*)(hp + j*4);
                int f = h*64 + j*4;
                float4 a4 = *(const float4*)&sm.bna[f];
                float4 b4 = *(const float4*)&sm.bnb[f];
                float4 w4 = *(const float4*)&sm.awl[f];
                part += fmaxf(v.x*a4.x + b4.x, 0.f)*w4.x
                      + fmaxf(v.y*a4.y + b4.y, 0.f)*w4.y
                      + fmaxf(v.z*a4.z + b4.z, 0.f)*w4.z
                      + fmaxf(v.w*a4.w + b4.w, 0.f)*w4.w;
            }
        }
        sm.red[t] = part;
    }
    __syncthreads();
    for (int l = t; l < n; l += 1024) sm.p0[l] = sm.red[2*l] + sm.red[2*l+1];
    __syncthreads();
    for (int l = t; l < n; l += 1024){
        int2 rc = sm.rbl[l];
        float acc = 0.f;
        for (int j = 0; j < rc.y; ++j){
            int2 e = sm.eds[rc.x + j];
            acc += __int_as_float(e.y) * sm.p0[e.x];
        }
        float dv = sm.dvv[l];
        sm.p1[l] = 2.f*(sm.p0[l]*dv*dv + dv*acc);
    }
    __syncthreads();
    for (int l = t; l < n; l += 1024){
        int2 rc = sm.rbl[l];
        float acc = 0.f;
        for (int j = 0; j < rc.y; ++j){
            int2 e = sm.eds[rc.x + j];
            acc += __int_as_float(e.y) * sm.p1[e.x];
        }
        float dv = sm.dvv[l];
        sm.p2[l] = ca2*(sm.p1[l]*dv*dv + dv*acc) + cc2*sm.p0[l];
    }
    __syncthreads();
    float t0v = th[0], t1v = th[1], t2c = th[2], t3v = th[3];
    for (int l = t; l < n; l += 1024){
        int2 rc = sm.rbl[l];
        float acc = 0.f;
        for (int j = 0; j < rc.y; ++j){
            int2 e = sm.eds[rc.x + j];
            acc += __int_as_float(e.y) * sm.p2[e.x];
        }
        float dv = sm.dvv[l];
        float tv = sm.p2[l]*dv*dv + dv*acc;
        float p3 = ca3*tv + cc3*sm.p1[l];
        sm.ss[l] = t0v*sm.p0[l] + t1v*sm.p1[l] + t2c*sm.p2[l] + t3v*p3;
    }
    __syncthreads();
    // ---- top-k by rank counting (exact jax.lax.top_k semantics) ----
    for (int l = t; l < n; l += 1024){
        float sl = sm.ss[l];
        int r = 0;
        for (int j = 0; j < n; j += 4){
            float4 s4 = *(const float4*)&sm.ss[j];
            r += (s4.x > sl) || (s4.x == sl && (j    ) < l);
            r += (s4.y > sl) || (s4.y == sl && (j + 1) < l);
            r += (s4.z > sl) || (s4.z == sl && (j + 2) < l);
            r += (s4.w > sl) || (s4.w == sl && (j + 3) < l);
        }
        if (r < k){
            sm.nid[l] = r;
            sm.si[r]  = l;
            float tv = tanhf(sl);
            sm.tss[r] = tv;
            siG[g*k + r]  = l;
            tssG[g*k + r] = tv;
        } else {
            sm.nid[l] = -1;
        }
    }
    __syncthreads();
    if (!last){
        if (t < k){
            int l = sm.si[t] & (n-1);
            int2 rc = sm.rbl[l];
            int c2 = 0;
            for (int j = 0; j < rc.y; ++j) c2 += (sm.nid[sm.eds[rc.x + j].x] >= 0);
            sm.cnt_[t] = c2;
        }
        __syncthreads();
        int c = (t < 256) ? ((t < k) ? sm.cnt_[t] : 0) : 0;
        int vscan = c;
        if (t < 256){
            int lane = t & 63;
            #pragma unroll
            for (int off = 1; off < 64; off <<= 1){
                int nv = __shfl_up(vscan, off);
                if (lane >= off) vscan += nv;
            }
            if (lane == 63) sm.wsum[t >> 6] = vscan;
        }
        __syncthreads();
        int beg = 0;
        if (t < k){
            int wv = t >> 6;
            int add = 0;
            for (int ww = 0; ww < wv; ++ww) add += sm.wsum[ww];
            vscan += add;
            beg = vscan - c;
            rb2n[g*k + t] = make_int2(g*4096 + beg, c);
            float dv = rsqrtf((float)c + 1.f);
            dinvn[g*k + t] = dv;
            sm.dvn[t] = dv;
        }
        __syncthreads();
        if (t < k){
            int l = sm.si[t] & (n-1);
            int2 rc = sm.rbl[l];
            int p = beg;
            for (int j = 0; j < rc.y; ++j){
                int ns = sm.nid[sm.eds[rc.x + j].x];
                if (ns >= 0){ csr[g*4096 + (p & 4095)] = make_int2(g*k + ns, __float_as_int(sm.dvn[ns])); ++p; }
            }
        }
        __syncthreads();
    }
    // ---- gather (BN+ReLU+tanh scale) + readout only; eds now dead -> scratch ----
    {
        int f4 = t & 31, rl = t >> 5;
        int f = f4*4;
        float4 a4 = *(const float4*)&sm.bna[f];
        float4 b4 = *(const float4*)&sm.bnb[f];
        float4 mx = make_float4(-3.4e38f,-3.4e38f,-3.4e38f,-3.4e38f);
        float4 smv = make_float4(0.f,0.f,0.f,0.f);
        for (int r = rl; r < k; r += 32){
            int old = sm.si[r] & (n-1);
            float4 hv = *(const float4*)(H + ((size_t)g*n + old)*HF + f);
            float ts = sm.tss[r];
            float4 v;
            v.x = fmaxf(hv.x*a4.x + b4.x, 0.f)*ts;
            v.y = fmaxf(hv.y*a4.y + b4.y, 0.f)*ts;
            v.z = fmaxf(hv.z*a4.z + b4.z, 0.f)*ts;
            v.w = fmaxf(hv.w*a4.w + b4.w, 0.f)*ts;
            mx.x = fmaxf(mx.x, v.x); mx.y = fmaxf(mx.y, v.y);
            mx.z = fmaxf(mx.z, v.z); mx.w = fmaxf(mx.w, v.w);
            smv.x += v.x; smv.y += v.y; smv.z += v.z; smv.w += v.w;
        }
        float* scr = (float*)sm.eds;
        *(float4*)&scr[rl*128 + f]        = mx;
        *(float4*)&scr[4096 + rl*128 + f] = smv;
        __syncthreads();
        if (t < 128){
            float m = -3.4e38f, s = 0.f;
            #pragma unroll
            for (int j = 0; j < 32; ++j){
                m = fmaxf(m, scr[j*128 + t]);
                s += scr[4096 + j*128 + t];
            }
            gacc[g*256 + t] += m;
            gacc[g*256 + 128 + t] += s / (float)k;
        }
    }
    if (last){
        __syncthreads();
        int c = t & 127, h = t >> 7;
        float s = 0.f;
        int k0 = h*32;
        #pragma unroll
        for (int kk = 0; kk < 32; ++kk)
            s += gacc[g*256 + k0 + kk] * lin1W[(k0 + kk)*128 + c];
        sm.red[t] = s;
        __syncthreads();
        if (t < 512) sm.red[t] += sm.red[t+512];
        __syncthreads();
        if (t < 256) sm.red[t] += sm.red[t+256];
        __syncthreads();
        if (t < 128){
            float v = (sm.red[t] + sm.red[t+128]) * 0.2f + lin1b[t];
            t1g[g*128 + t] = v;
            atomicAdd(&statsH[t], v);
            atomicAdd(&statsH[128+t], v*v);
        }
    }
}

// ---------------- head tail kernels ----------------
__global__ __launch_bounds__(128) void k_head2(const float* __restrict__ t1, const float* __restrict__ gw,
                                               const float* __restrict__ gb, const float* __restrict__ W2,
                                               const float* __restrict__ b2, float* __restrict__ sh,
                                               float* __restrict__ t2){
    int r = blockIdx.x, t = threadIdx.x;
    int cc = t & 63, h = t >> 6;
    __shared__ float row[128];
    __shared__ float red[128];
    {
        float mean = sh[t] * (1.f/128.f);
        float var  = sh[128+t]*(1.f/128.f) - mean*mean;
        float iv   = rsqrtf(var + 1e-5f);
        float v = (t1[r*128+t] - mean)*iv*gw[t] + gb[t];
        row[t] = fmaxf(v, 0.f);
    }
    __syncthreads();
    float s = 0.f;
    #pragma unroll
    for (int kk = 0; kk < 64; ++kk)
        s += row[h*64+kk] * W2[(h*64+kk)*64 + cc];
    red[t] = s;
    __syncthreads();
    if (h == 0){
        float v = red[cc] + red[cc+64] + b2[cc];
        t2[r*64+cc] = v;
        atomicAdd(&sh[256+cc], v);
        atomicAdd(&sh[320+cc], v*v);
    }
}
__global__ __launch_bounds__(64) void k_head3(const float* __restrict__ t2, const float* __restrict__ gw,
                                              const float* __restrict__ gb, const float* __restrict__ W3,
                                              const float* __restrict__ b3, const float* __restrict__ sh,
                                              float* __restrict__ out){
    int r = blockIdx.x, t = threadIdx.x;
    float mean = sh[256+t]*(1.f/128.f);
    float var  = sh[320+t]*(1.f/128.f) - mean*mean;
    float iv   = rsqrtf(var + 1e-5f);
    float v = fmaxf((t2[r*64+t]-mean)*iv*gw[t] + gb[t], 0.f);
    float lg[10];
    #pragma unroll
    for (int j = 0; j < 10; ++j){
        float p = v * W3[t*10 + j];
        for (int off = 32; off; off >>= 1) p += __shfl_down(p, off);
        lg[j] = p;
    }
    if (t == 0){
        float m = -3.4e38f;
        #pragma unroll
        for (int j = 0; j < 10; ++j){ lg[j] += b3[j]; m = fmaxf(m, lg[j]); }
        float se = 0.f;
        #pragma unroll
        for (int j = 0; j < 10; ++j) se += expf(lg[j] - m);
        float l = logf(se) + m;
        #pragma unroll
        for (int j = 0; j < 10; ++j) out[r*10 + j] = lg[j] - l;
    }
}

extern "C" void kernel_launch(void* const* d_in, const int* in_sizes, int n_in,
                              void* d_out, int out_size, void* d_ws, size_t ws_size,
                              hipStream_t stream){
    const float* x     = (const float*)d_in[0];
    const float* convW = (const float*)d_in[1];
    const float* convb = (const float*)d_in[2];
    const float* bnW   = (const float*)d_in[3];
    const float* bnB   = (const float*)d_in[4];
    const float* bn7W  = (const float*)d_in[5];
    const float* bn7B  = (const float*)d_in[6];
    const float* attW  = (const float*)d_in[7];
    const float* theta = (const float*)d_in[8];
    const float* lin1W = (const float*)d_in[9];
    const float* lin1b = (const float*)d_in[10];
    const float* lin2W = (const float*)d_in[11];
    const float* lin2b = (const float*)d_in[12];
    const float* lin3W = (const float*)d_in[13];
    const float* lin3b = (const float*)d_in[14];
    const int*   src0  = (const int*)d_in[15];
    const int*   dst0  = (const int*)d_in[16];

    char* base = (char*)d_ws;
    size_t off = 0;
    auto take = [&](size_t bytes) -> void* {
        void* p = base + off;
        off = (off + bytes + 255) & ~(size_t)255;
        return p;
    };
    float* bufGP = (float*)take((size_t)N0G*HF*4);
    float* bufHA = (float*)take((size_t)N0G*HF*4);
    float* bufHB = (float*)take((size_t)(N0G/2)*HF*4);
    int2*  csr_p = (int2*) take((size_t)ETOT*8);
    int2*  rb2A  = (int2*) take((size_t)N0G*8);
    int2*  rb2B  = (int2*) take((size_t)N0G*8);
    float* dinvA = (float*)take((size_t)N0G*4);
    float* dinvB = (float*)take((size_t)N0G*4);
    int*   siG   = (int*)  take((size_t)(N0G/2)*4);
    float* tssG  = (float*)take((size_t)(N0G/2)*4);
    float* st[3];
    st[0] = (float*)take(STSZ*4);
    st[1] = (float*)take(STSZ*4);
    st[2] = (float*)take(STSZ*4);
    float* gacc  = (float*)take((size_t)B_GRAPH*256*4);
    float* t1    = (float*)take((size_t)B_GRAPH*128*4);
    float* t2    = (float*)take((size_t)B_GRAPH*64*4);
    float* statsH= (float*)take(384*4);

    auto coef = [](int kk, float& ca, float& cc){
        double a = 1.0, b = 1.0;
        double c0 = 2.0*kk*(kk+a+b)*(2.0*kk+a+b-2.0);
        double c1 = (2.0*kk+a+b-1.0)*(2.0*kk+a+b)*(2.0*kk+a+b-2.0);
        double c3 = 2.0*(kk+a-1.0)*(kk+b-1.0)*(2.0*kk+a+b);
        ca = (float)(c1/c0); cc = (float)(-c3/c0);
    };
    float ca2, cc2, ca3, cc3;
    coef(2, ca2, cc2);
    coef(3, ca3, cc3);

    k_init_gemm<<<128 + 512, 256, 0, stream>>>(x, convW, bufGP,
                                               src0, dst0, csr_p, rb2A, dinvA,
                                               gacc, statsH, st[0], st[1], st[2]);
    k_prop_lds<512><<<512, 512, 0, stream>>>(bufGP, convb, rb2A, csr_p, dinvA, bufHA, st[0]);

    float* G = bufGP + (size_t)4*1024*1024;   // G region for levels >= 1

    for (int i = 0; i < 5; ++i){
        int n = 512 >> i;
        int kk = n >> 1;
        int Nn = B_GRAPH*n;
        float invN = 1.0f/(float)Nn;
        int2*  rb_cur = (i & 1) ? rb2B : rb2A;
        int2*  rb_nxt = (i & 1) ? rb2A : rb2B;
        float* dv_cur = (i & 1) ? dinvB : dinvA;
        float* dv_nxt = (i & 1) ? dinvA : dinvB;
        float* Hcur = (i & 1) ? bufHB : bufHA;
        float* Hnxt = (i & 1) ? bufHA : bufHB;

        k_pool<<<B_GRAPH, 1024, 0, stream>>>(Hcur, st[i % 3], bnW + i*HF, bnB + i*HF, attW + i*HF,
                                             theta + i*4, rb_cur, csr_p, dv_cur,
                                             gacc, rb_nxt, dv_nxt,
                                             st[(i + 1) % 3], siG, tssG,
                                             lin1W, lin1b, t1, statsH,
                                             invN, ca2, cc2, ca3, cc3, n, (i == 4) ? 1 : 0);
        if (i < 4){
            int wnext = i + 1;
            int rows = B_GRAPH * kk;
            int lk = 8 - i;          // log2(kk): 8,7,6,5
            int ln = 9 - i;          // log2(n):  9,8,7,6
            const float* Wn = convW + (size_t)wnext*HF*HF;
            if (i == 0)
                k_gemm_gs<8><<<rows/128, 256, 0, stream>>>(Hcur, st[i % 3], bnW + i*HF, bnB + i*HF,
                                                           siG, tssG, Wn, G, invN, lk, ln);
            else if (i == 1)
                k_gemm_gs<4><<<rows/64, 256, 0, stream>>>(Hcur, st[i % 3], bnW + i*HF, bnB + i*HF,
                                                          siG, tssG, Wn, G, invN, lk, ln);
            else
                k_gemm_g32<<<rows/32, 256, 0, stream>>>(Hcur, st[i % 3], bnW + i*HF, bnB + i*HF,
                                                        siG, tssG, Wn, G, invN, lk, ln);
            if (kk == 256){
                k_prop_lds<256><<<512, 512, 0, stream>>>(G, convb + wnext*HF, rb_nxt, csr_p, dv_nxt,
                                                         Hnxt, st[(i + 1) % 3]);
            } else {
                int lbn = (kk == 128) ? 4 : (kk == 64) ? 3 : 2;
                k_prop_stats<<<rows/8, 256, 0, stream>>>(G, convb + wnext*HF, rb_nxt, csr_p, dv_nxt,
                                                         Hnxt, st[(i + 1) % 3], kk, lbn, rows);
            }
        }
    }

    k_head2<<<B_GRAPH, 128, 0, stream>>>(t1, bnW + 5*HF, bnB + 5*HF, lin2W, lin2b, statsH, t2);
    k_head3<<<B_GRAPH, 64, 0, stream>>>(t2, bn7W, bn7B, lin3W, lin3b, statsH, (float*)d_out);
}